// Round 1
// baseline (1072.076 us; speedup 1.0000x reference)
//
#include <hip/hip_runtime.h>

// GCN: 4x GCNConv(128->128, symmetric norm, self-loops) + FC(128->32) + global mean pool.
// Strategy: build CSR-by-dst once (histogram + scan + fill), then per layer:
//   gemm128: hW = h @ W           (fp32, LDS-staged H tile, W via L2)
//   agg:     h'[i] = b + dinv[i]^2*hW[i] + sum_e w_e * hW[src_e]   (gather, no atomics)
// Then fc, pool (atomics over 64x32 accum), finalize (divide by counts).

#define N_NODES 50000
#define N_EDGES 600000
#define D 128
#define D_OUT 32
#define N_GRAPHS 64
#define SCAN_B 1024
#define N_SCAN_BLOCKS ((N_NODES + SCAN_B - 1) / SCAN_B)  // 49

// ---------------- graph preprocessing ----------------

__global__ void hist_kernel(const int* __restrict__ dst, int* __restrict__ indeg) {
    int e = blockIdx.x * blockDim.x + threadIdx.x;
    if (e < N_EDGES) atomicAdd(&indeg[dst[e]], 1);
}

__global__ void scan_block_sum(const int* __restrict__ indeg, int* __restrict__ bsum) {
    __shared__ int sdata[SCAN_B];
    int i = blockIdx.x * SCAN_B + threadIdx.x;
    sdata[threadIdx.x] = (i < N_NODES) ? indeg[i] : 0;
    __syncthreads();
    for (int s = SCAN_B / 2; s > 0; s >>= 1) {
        if (threadIdx.x < s) sdata[threadIdx.x] += sdata[threadIdx.x + s];
        __syncthreads();
    }
    if (threadIdx.x == 0) bsum[blockIdx.x] = sdata[0];
}

__global__ void scan_partials(const int* __restrict__ bsum, int* __restrict__ boff) {
    int t = threadIdx.x;  // 64 threads, N_SCAN_BLOCKS=49 <= 64
    int orig = (t < N_SCAN_BLOCKS) ? bsum[t] : 0;
    int v = orig;
    for (int off = 1; off < 64; off <<= 1) {
        int u = __shfl_up(v, off);
        if (t >= off) v += u;
    }
    if (t < N_SCAN_BLOCKS) boff[t] = v - orig;  // exclusive
}

__global__ void scan_within(const int* __restrict__ indeg, const int* __restrict__ boff,
                            int* __restrict__ row_off) {
    __shared__ int sdata[SCAN_B];
    int i = blockIdx.x * SCAN_B + threadIdx.x;
    int orig = (i < N_NODES) ? indeg[i] : 0;
    sdata[threadIdx.x] = orig;
    __syncthreads();
    for (int off = 1; off < SCAN_B; off <<= 1) {
        int add = (threadIdx.x >= (unsigned)off) ? sdata[threadIdx.x - off] : 0;
        __syncthreads();
        if (threadIdx.x >= (unsigned)off) sdata[threadIdx.x] += add;
        __syncthreads();
    }
    if (i < N_NODES) row_off[i] = boff[blockIdx.x] + sdata[threadIdx.x] - orig;  // exclusive
}

__global__ void dinv_kernel(const int* __restrict__ indeg, float* __restrict__ dinv) {
    int i = blockIdx.x * blockDim.x + threadIdx.x;
    if (i < N_NODES) dinv[i] = rsqrtf((float)(indeg[i] + 1));  // +1 self-loop; deg>=1 always
}

__global__ void fill_kernel(const int* __restrict__ src, const int* __restrict__ dst,
                            const int* __restrict__ row_off, int* __restrict__ cursor,
                            const float* __restrict__ dinv,
                            int* __restrict__ csr_src, float* __restrict__ csr_w) {
    int e = blockIdx.x * blockDim.x + threadIdx.x;
    if (e >= N_EDGES) return;
    int d = dst[e], s = src[e];
    int pos = atomicAdd(&cursor[d], 1);
    int slot = row_off[d] + pos;
    csr_src[slot] = s;
    csr_w[slot] = dinv[s] * dinv[d];
}

// ---------------- dense compute ----------------

// out[row][col] = sum_k H[row][k] * W[k][col]; 32-row tile/block, 128 threads = 1/col.
__global__ __launch_bounds__(128) void gemm128(const float* __restrict__ H,
                                               const float* __restrict__ W,
                                               float* __restrict__ out) {
    __shared__ float4 Hs4[32 * 32];  // 32 rows x 128 floats
    int t = threadIdx.x;             // col
    int rbase = blockIdx.x * 32;
    const float4* H4 = (const float4*)H;
    for (int i = 0; i < 8; ++i) {
        int idx = i * 128 + t;         // 0..1023
        int row = rbase + (idx >> 5);  // local row = idx/32
        int k4 = idx & 31;
        Hs4[idx] = (row < N_NODES) ? H4[row * 32 + k4] : make_float4(0.f, 0.f, 0.f, 0.f);
    }
    __syncthreads();

    float acc[32];
#pragma unroll
    for (int r = 0; r < 32; ++r) acc[r] = 0.f;

    for (int k = 0; k < 128; k += 4) {
        float w0 = W[(k + 0) * 128 + t];
        float w1 = W[(k + 1) * 128 + t];
        float w2 = W[(k + 2) * 128 + t];
        float w3 = W[(k + 3) * 128 + t];
#pragma unroll
        for (int r = 0; r < 32; ++r) {
            float4 hv = Hs4[r * 32 + (k >> 2)];  // LDS broadcast, conflict-free
            acc[r] += hv.x * w0 + hv.y * w1 + hv.z * w2 + hv.w * w3;
        }
    }
    for (int r = 0; r < 32; ++r) {
        int row = rbase + r;
        if (row < N_NODES) out[row * 128 + t] = acc[r];
    }
}

// One wave per node; lane handles 2 dims (float2). out = b + dinv^2*hW[i] + sum w_e*hW[src_e].
__global__ __launch_bounds__(256) void agg_kernel(const float* __restrict__ hW,
                                                  const float* __restrict__ bias,
                                                  const float* __restrict__ dinv,
                                                  const int* __restrict__ row_off,
                                                  const int* __restrict__ indeg,
                                                  const int* __restrict__ csr_src,
                                                  const float* __restrict__ csr_w,
                                                  float* __restrict__ out) {
    int wave = threadIdx.x >> 6;
    int lane = threadIdx.x & 63;
    int n = blockIdx.x * 4 + wave;
    if (n >= N_NODES) return;
    const float2* hW2 = (const float2*)hW;
    float2 b2 = ((const float2*)bias)[lane];
    float di = dinv[n];
    float sw = di * di;
    float2 hv = hW2[n * 64 + lane];
    float2 acc = make_float2(b2.x + sw * hv.x, b2.y + sw * hv.y);
    int beg = row_off[n];
    int cnt = indeg[n];
    for (int e = beg; e < beg + cnt; ++e) {
        int s = csr_src[e];     // broadcast load
        float w = csr_w[e];
        float2 v = hW2[s * 64 + lane];  // 512B coalesced gather
        acc.x += w * v.x;
        acc.y += w * v.y;
    }
    ((float2*)out)[n * 64 + lane] = acc;
}

// FC 128->32 with bias. 64 rows/block; thread = (col = t&31, rowgroup = t>>5 of 8 rows).
__global__ __launch_bounds__(256) void fc_kernel(const float* __restrict__ H,
                                                 const float* __restrict__ Wfc,
                                                 const float* __restrict__ bfc,
                                                 float* __restrict__ out) {
    __shared__ float Ws[128 * 32];
    int t = threadIdx.x;
    for (int i = 0; i < 16; ++i) Ws[i * 256 + t] = Wfc[i * 256 + t];
    __syncthreads();
    int col = t & 31, rg = t >> 5;
    int row0 = blockIdx.x * 64 + rg * 8;
    float bv = bfc[col];
    float acc[8];
#pragma unroll
    for (int r = 0; r < 8; ++r) acc[r] = bv;
    const float4* H4 = (const float4*)H;
    for (int k4 = 0; k4 < 32; ++k4) {
        float4 hv[8];
#pragma unroll
        for (int r = 0; r < 8; ++r) {
            int row = row0 + r;
            hv[r] = (row < N_NODES) ? H4[row * 32 + k4] : make_float4(0.f, 0.f, 0.f, 0.f);
        }
        float w0 = Ws[(k4 * 4 + 0) * 32 + col];
        float w1 = Ws[(k4 * 4 + 1) * 32 + col];
        float w2 = Ws[(k4 * 4 + 2) * 32 + col];
        float w3 = Ws[(k4 * 4 + 3) * 32 + col];
#pragma unroll
        for (int r = 0; r < 8; ++r)
            acc[r] += hv[r].x * w0 + hv[r].y * w1 + hv[r].z * w2 + hv[r].w * w3;
    }
    for (int r = 0; r < 8; ++r) {
        int row = row0 + r;
        if (row < N_NODES) out[row * 32 + col] = acc[r];
    }
}

// Pool: thread per (node,dim); pair-reduce across the 2 nodes in a wave (batch sorted).
__global__ void pool_kernel(const float* __restrict__ hfc, const int* __restrict__ batch,
                            float* __restrict__ pool) {
    int idx = blockIdx.x * 256 + threadIdx.x;  // grid exact: 50000*32 / 256
    int node = idx >> 5, d = idx & 31;
    int lane = threadIdx.x & 63;
    int g = batch[node];
    float val = hfc[idx];
    float oval = __shfl(val, lane ^ 32);
    int og = __shfl(g, lane ^ 32);
    if (g == og) {
        if (lane < 32) atomicAdd(&pool[g * 32 + d], val + oval);
    } else {
        atomicAdd(&pool[g * 32 + d], val);
    }
}

__global__ void cnt_kernel(const int* __restrict__ batch, float* __restrict__ cnt) {
    int i = blockIdx.x * blockDim.x + threadIdx.x;
    if (i < N_NODES) atomicAdd(&cnt[batch[i]], 1.0f);
}

__global__ void final_kernel(const float* __restrict__ pool, const float* __restrict__ cnt,
                             float* __restrict__ out) {
    int idx = blockIdx.x * blockDim.x + threadIdx.x;
    if (idx < N_GRAPHS * D_OUT) {
        int g = idx >> 5;
        out[idx] = pool[idx] / fmaxf(cnt[g], 1.0f);
    }
}

// ---------------- launch ----------------

static inline size_t align_up(size_t x) { return (x + 255) & ~(size_t)255; }

extern "C" void kernel_launch(void* const* d_in, const int* in_sizes, int n_in,
                              void* d_out, int out_size, void* d_ws, size_t ws_size,
                              hipStream_t stream) {
    const float* x = (const float*)d_in[0];
    const int* edge_index = (const int*)d_in[1];
    const int* batch = (const int*)d_in[2];
    const float* W1 = (const float*)d_in[3];
    const float* b1 = (const float*)d_in[4];
    const float* W2 = (const float*)d_in[5];
    const float* b2 = (const float*)d_in[6];
    const float* W3 = (const float*)d_in[7];
    const float* b3 = (const float*)d_in[8];
    const float* W4 = (const float*)d_in[9];
    const float* b4 = (const float*)d_in[10];
    const float* fcW = (const float*)d_in[11];
    const float* fcb = (const float*)d_in[12];
    float* out = (float*)d_out;

    const int* src = edge_index;             // edge_index[0,:]
    const int* dst = edge_index + N_EDGES;   // edge_index[1,:]

    char* base = (char*)d_ws;
    size_t o = 0;
    float* hW = (float*)(base + o);      o = align_up(o + (size_t)N_NODES * D * 4);
    float* h = (float*)(base + o);       o = align_up(o + (size_t)N_NODES * D * 4);
    int* csr_src = (int*)(base + o);     o = align_up(o + (size_t)N_EDGES * 4);
    float* csr_w = (float*)(base + o);   o = align_up(o + (size_t)N_EDGES * 4);
    int* row_off = (int*)(base + o);     o = align_up(o + (size_t)N_NODES * 4);
    int* indeg = (int*)(base + o);       o = align_up(o + (size_t)N_NODES * 4);
    int* cursor = (int*)(base + o);      o = align_up(o + (size_t)N_NODES * 4);
    float* dinv = (float*)(base + o);    o = align_up(o + (size_t)N_NODES * 4);
    int* bsum = (int*)(base + o);        o = align_up(o + 256);
    int* boff = (int*)(base + o);        o = align_up(o + 256);
    float* hfc = (float*)(base + o);     o = align_up(o + (size_t)N_NODES * D_OUT * 4);
    float* pool = (float*)(base + o);    o = align_up(o + (size_t)N_GRAPHS * D_OUT * 4);
    float* cnt = (float*)(base + o);     o = align_up(o + (size_t)N_GRAPHS * 4);

    // zero accumulators (ws is poisoned 0xAA before every call)
    hipMemsetAsync(indeg, 0, (size_t)N_NODES * 4, stream);
    hipMemsetAsync(cursor, 0, (size_t)N_NODES * 4, stream);
    hipMemsetAsync(pool, 0, (size_t)N_GRAPHS * D_OUT * 4, stream);
    hipMemsetAsync(cnt, 0, (size_t)N_GRAPHS * 4, stream);

    // graph preprocessing
    hist_kernel<<<(N_EDGES + 255) / 256, 256, 0, stream>>>(dst, indeg);
    scan_block_sum<<<N_SCAN_BLOCKS, SCAN_B, 0, stream>>>(indeg, bsum);
    scan_partials<<<1, 64, 0, stream>>>(bsum, boff);
    scan_within<<<N_SCAN_BLOCKS, SCAN_B, 0, stream>>>(indeg, boff, row_off);
    dinv_kernel<<<(N_NODES + 255) / 256, 256, 0, stream>>>(indeg, dinv);
    fill_kernel<<<(N_EDGES + 255) / 256, 256, 0, stream>>>(src, dst, row_off, cursor, dinv,
                                                           csr_src, csr_w);

    const int gemm_grid = (N_NODES + 31) / 32;   // 1563
    const int agg_grid = (N_NODES + 3) / 4;      // 12500

    // layer 1
    gemm128<<<gemm_grid, 128, 0, stream>>>(x, W1, hW);
    agg_kernel<<<agg_grid, 256, 0, stream>>>(hW, b1, dinv, row_off, indeg, csr_src, csr_w, h);
    // layer 2
    gemm128<<<gemm_grid, 128, 0, stream>>>(h, W2, hW);
    agg_kernel<<<agg_grid, 256, 0, stream>>>(hW, b2, dinv, row_off, indeg, csr_src, csr_w, h);
    // layer 3
    gemm128<<<gemm_grid, 128, 0, stream>>>(h, W3, hW);
    agg_kernel<<<agg_grid, 256, 0, stream>>>(hW, b3, dinv, row_off, indeg, csr_src, csr_w, h);
    // layer 4
    gemm128<<<gemm_grid, 128, 0, stream>>>(h, W4, hW);
    agg_kernel<<<agg_grid, 256, 0, stream>>>(hW, b4, dinv, row_off, indeg, csr_src, csr_w, h);

    // head
    fc_kernel<<<(N_NODES + 63) / 64, 256, 0, stream>>>(h, fcW, fcb, hfc);
    pool_kernel<<<(N_NODES * D_OUT) / 256, 256, 0, stream>>>(hfc, batch, pool);
    cnt_kernel<<<(N_NODES + 255) / 256, 256, 0, stream>>>(batch, cnt);
    final_kernel<<<(N_GRAPHS * D_OUT + 255) / 256, 256, 0, stream>>>(pool, cnt, out);
}

// Round 2
// 779.586 us; speedup vs baseline: 1.3752x; 1.3752x over previous
//
#include <hip/hip_runtime.h>

// GCN: 4x GCNConv(128->128, symmetric norm, self-loops) + FC(128->32) + global mean pool.
// Strategy: build CSR-by-dst once (histogram + scan + fill), then per layer:
//   gemm128: hW = h @ W           (fp32, LDS-staged H tile, W via L2)
//   agg:     h'[i] = b + dinv[i]^2*hW[i] + sum_e w_e * hW[src_e]   (gather, no atomics)
// Then fc, segmented pool (batch is SORTED -> register-accumulate runs, atomics only at
// graph boundaries; R1 showed same-address float atomics cost ~384ns/op chain -> 300us cnt).

#define N_NODES 50000
#define N_EDGES 600000
#define D 128
#define D_OUT 32
#define N_GRAPHS 64
#define SCAN_B 1024
#define N_SCAN_BLOCKS ((N_NODES + SCAN_B - 1) / SCAN_B)  // 49
#define POOL_L 64
#define POOL_SLOTS ((N_NODES + POOL_L - 1) / POOL_L)     // 782
#define POOL_BLOCKS ((POOL_SLOTS + 7) / 8)               // 98

// ---------------- graph preprocessing ----------------

__global__ void hist_kernel(const int* __restrict__ dst, int* __restrict__ indeg) {
    int e = blockIdx.x * blockDim.x + threadIdx.x;
    if (e < N_EDGES) atomicAdd(&indeg[dst[e]], 1);
}

__global__ void scan_block_sum(const int* __restrict__ indeg, int* __restrict__ bsum) {
    __shared__ int sdata[SCAN_B];
    int i = blockIdx.x * SCAN_B + threadIdx.x;
    sdata[threadIdx.x] = (i < N_NODES) ? indeg[i] : 0;
    __syncthreads();
    for (int s = SCAN_B / 2; s > 0; s >>= 1) {
        if (threadIdx.x < s) sdata[threadIdx.x] += sdata[threadIdx.x + s];
        __syncthreads();
    }
    if (threadIdx.x == 0) bsum[blockIdx.x] = sdata[0];
}

__global__ void scan_partials(const int* __restrict__ bsum, int* __restrict__ boff) {
    int t = threadIdx.x;  // 64 threads, N_SCAN_BLOCKS=49 <= 64
    int orig = (t < N_SCAN_BLOCKS) ? bsum[t] : 0;
    int v = orig;
    for (int off = 1; off < 64; off <<= 1) {
        int u = __shfl_up(v, off);
        if (t >= off) v += u;
    }
    if (t < N_SCAN_BLOCKS) boff[t] = v - orig;  // exclusive
}

__global__ void scan_within(const int* __restrict__ indeg, const int* __restrict__ boff,
                            int* __restrict__ row_off) {
    __shared__ int sdata[SCAN_B];
    int i = blockIdx.x * SCAN_B + threadIdx.x;
    int orig = (i < N_NODES) ? indeg[i] : 0;
    sdata[threadIdx.x] = orig;
    __syncthreads();
    for (int off = 1; off < SCAN_B; off <<= 1) {
        int add = (threadIdx.x >= (unsigned)off) ? sdata[threadIdx.x - off] : 0;
        __syncthreads();
        if (threadIdx.x >= (unsigned)off) sdata[threadIdx.x] += add;
        __syncthreads();
    }
    if (i < N_NODES) row_off[i] = boff[blockIdx.x] + sdata[threadIdx.x] - orig;  // exclusive
}

__global__ void dinv_kernel(const int* __restrict__ indeg, float* __restrict__ dinv) {
    int i = blockIdx.x * blockDim.x + threadIdx.x;
    if (i < N_NODES) dinv[i] = rsqrtf((float)(indeg[i] + 1));  // +1 self-loop; deg>=1 always
}

__global__ void fill_kernel(const int* __restrict__ src, const int* __restrict__ dst,
                            const int* __restrict__ row_off, int* __restrict__ cursor,
                            const float* __restrict__ dinv,
                            int* __restrict__ csr_src, float* __restrict__ csr_w) {
    int e = blockIdx.x * blockDim.x + threadIdx.x;
    if (e >= N_EDGES) return;
    int d = dst[e], s = src[e];
    int pos = atomicAdd(&cursor[d], 1);
    int slot = row_off[d] + pos;
    csr_src[slot] = s;
    csr_w[slot] = dinv[s] * dinv[d];
}

// ---------------- dense compute ----------------

// out[row][col] = sum_k H[row][k] * W[k][col]; 32-row tile/block, 128 threads = 1/col.
__global__ __launch_bounds__(128) void gemm128(const float* __restrict__ H,
                                               const float* __restrict__ W,
                                               float* __restrict__ out) {
    __shared__ float4 Hs4[32 * 32];  // 32 rows x 128 floats
    int t = threadIdx.x;             // col
    int rbase = blockIdx.x * 32;
    const float4* H4 = (const float4*)H;
    for (int i = 0; i < 8; ++i) {
        int idx = i * 128 + t;         // 0..1023
        int row = rbase + (idx >> 5);  // local row = idx/32
        int k4 = idx & 31;
        Hs4[idx] = (row < N_NODES) ? H4[row * 32 + k4] : make_float4(0.f, 0.f, 0.f, 0.f);
    }
    __syncthreads();

    float acc[32];
#pragma unroll
    for (int r = 0; r < 32; ++r) acc[r] = 0.f;

    for (int k = 0; k < 128; k += 4) {
        float w0 = W[(k + 0) * 128 + t];
        float w1 = W[(k + 1) * 128 + t];
        float w2 = W[(k + 2) * 128 + t];
        float w3 = W[(k + 3) * 128 + t];
#pragma unroll
        for (int r = 0; r < 32; ++r) {
            float4 hv = Hs4[r * 32 + (k >> 2)];  // LDS broadcast, conflict-free
            acc[r] += hv.x * w0 + hv.y * w1 + hv.z * w2 + hv.w * w3;
        }
    }
    for (int r = 0; r < 32; ++r) {
        int row = rbase + r;
        if (row < N_NODES) out[row * 128 + t] = acc[r];
    }
}

// One wave per node; lane handles 2 dims (float2). out = b + dinv^2*hW[i] + sum w_e*hW[src_e].
__global__ __launch_bounds__(256) void agg_kernel(const float* __restrict__ hW,
                                                  const float* __restrict__ bias,
                                                  const float* __restrict__ dinv,
                                                  const int* __restrict__ row_off,
                                                  const int* __restrict__ indeg,
                                                  const int* __restrict__ csr_src,
                                                  const float* __restrict__ csr_w,
                                                  float* __restrict__ out) {
    int wave = threadIdx.x >> 6;
    int lane = threadIdx.x & 63;
    int n = blockIdx.x * 4 + wave;
    if (n >= N_NODES) return;
    const float2* hW2 = (const float2*)hW;
    float2 b2 = ((const float2*)bias)[lane];
    float di = dinv[n];
    float sw = di * di;
    float2 hv = hW2[n * 64 + lane];
    float2 acc = make_float2(b2.x + sw * hv.x, b2.y + sw * hv.y);
    int beg = row_off[n];
    int cnt = indeg[n];
    for (int e = beg; e < beg + cnt; ++e) {
        int s = csr_src[e];     // broadcast load
        float w = csr_w[e];
        float2 v = hW2[s * 64 + lane];  // 512B coalesced gather
        acc.x += w * v.x;
        acc.y += w * v.y;
    }
    ((float2*)out)[n * 64 + lane] = acc;
}

// FC 128->32 with bias. 64 rows/block; thread = (col = t&31, rowgroup = t>>5 of 8 rows).
__global__ __launch_bounds__(256) void fc_kernel(const float* __restrict__ H,
                                                 const float* __restrict__ Wfc,
                                                 const float* __restrict__ bfc,
                                                 float* __restrict__ out) {
    __shared__ float Ws[128 * 32];
    int t = threadIdx.x;
    for (int i = 0; i < 16; ++i) Ws[i * 256 + t] = Wfc[i * 256 + t];
    __syncthreads();
    int col = t & 31, rg = t >> 5;
    int row0 = blockIdx.x * 64 + rg * 8;
    float bv = bfc[col];
    float acc[8];
#pragma unroll
    for (int r = 0; r < 8; ++r) acc[r] = bv;
    const float4* H4 = (const float4*)H;
    for (int k4 = 0; k4 < 32; ++k4) {
        float4 hv[8];
#pragma unroll
        for (int r = 0; r < 8; ++r) {
            int row = row0 + r;
            hv[r] = (row < N_NODES) ? H4[row * 32 + k4] : make_float4(0.f, 0.f, 0.f, 0.f);
        }
        float w0 = Ws[(k4 * 4 + 0) * 32 + col];
        float w1 = Ws[(k4 * 4 + 1) * 32 + col];
        float w2 = Ws[(k4 * 4 + 2) * 32 + col];
        float w3 = Ws[(k4 * 4 + 3) * 32 + col];
#pragma unroll
        for (int r = 0; r < 8; ++r)
            acc[r] += hv[r].x * w0 + hv[r].y * w1 + hv[r].z * w2 + hv[r].w * w3;
    }
    for (int r = 0; r < 8; ++r) {
        int row = row0 + r;
        if (row < N_NODES) out[row * 32 + col] = acc[r];
    }
}

// Segmented pool over SORTED batch ids: thread (slot, dim) owns POOL_L contiguous nodes,
// accumulates in-register, one atomicAdd per graph-boundary crossing (~1.05/thread).
__global__ __launch_bounds__(256) void pool_seg_kernel(const float* __restrict__ hfc,
                                                       const int* __restrict__ batch,
                                                       float* __restrict__ pool) {
    int t = threadIdx.x;
    int d = t & 31;
    int slot = blockIdx.x * 8 + (t >> 5);
    int n0 = slot * POOL_L;
    if (n0 >= N_NODES) return;
    int n1 = n0 + POOL_L;
    if (n1 > N_NODES) n1 = N_NODES;
    int gprev = batch[n0];  // broadcast across the 32 lanes of this slot
    float acc = 0.f;
    for (int n = n0; n < n1; ++n) {
        int g = batch[n];
        if (g != gprev) {
            atomicAdd(&pool[gprev * 32 + d], acc);
            acc = 0.f;
            gprev = g;
        }
        acc += hfc[n * 32 + d];  // 128B coalesced per slot
    }
    atomicAdd(&pool[gprev * 32 + d], acc);
}

// counts via binary search on sorted batch: count[g] = lb(g+1) - lb(g). 64 threads, ~2us.
__global__ void cnt_bs_kernel(const int* __restrict__ batch, float* __restrict__ cnt) {
    int g = threadIdx.x;
    if (g >= N_GRAPHS) return;
    int lo = 0, hi = N_NODES;
    while (lo < hi) { int mid = (lo + hi) >> 1; if (batch[mid] < g) lo = mid + 1; else hi = mid; }
    int lo2 = lo, hi2 = N_NODES;
    while (lo2 < hi2) { int mid = (lo2 + hi2) >> 1; if (batch[mid] < g + 1) lo2 = mid + 1; else hi2 = mid; }
    cnt[g] = (float)(lo2 - lo);
}

__global__ void final_kernel(const float* __restrict__ pool, const float* __restrict__ cnt,
                             float* __restrict__ out) {
    int idx = blockIdx.x * blockDim.x + threadIdx.x;
    if (idx < N_GRAPHS * D_OUT) {
        int g = idx >> 5;
        out[idx] = pool[idx] / fmaxf(cnt[g], 1.0f);
    }
}

// ---------------- launch ----------------

static inline size_t align_up(size_t x) { return (x + 255) & ~(size_t)255; }

extern "C" void kernel_launch(void* const* d_in, const int* in_sizes, int n_in,
                              void* d_out, int out_size, void* d_ws, size_t ws_size,
                              hipStream_t stream) {
    const float* x = (const float*)d_in[0];
    const int* edge_index = (const int*)d_in[1];
    const int* batch = (const int*)d_in[2];
    const float* W1 = (const float*)d_in[3];
    const float* b1 = (const float*)d_in[4];
    const float* W2 = (const float*)d_in[5];
    const float* b2 = (const float*)d_in[6];
    const float* W3 = (const float*)d_in[7];
    const float* b3 = (const float*)d_in[8];
    const float* W4 = (const float*)d_in[9];
    const float* b4 = (const float*)d_in[10];
    const float* fcW = (const float*)d_in[11];
    const float* fcb = (const float*)d_in[12];
    float* out = (float*)d_out;

    const int* src = edge_index;             // edge_index[0,:]
    const int* dst = edge_index + N_EDGES;   // edge_index[1,:]

    char* base = (char*)d_ws;
    size_t o = 0;
    float* hW = (float*)(base + o);      o = align_up(o + (size_t)N_NODES * D * 4);
    float* h = (float*)(base + o);       o = align_up(o + (size_t)N_NODES * D * 4);
    int* csr_src = (int*)(base + o);     o = align_up(o + (size_t)N_EDGES * 4);
    float* csr_w = (float*)(base + o);   o = align_up(o + (size_t)N_EDGES * 4);
    int* row_off = (int*)(base + o);     o = align_up(o + (size_t)N_NODES * 4);
    int* indeg = (int*)(base + o);       o = align_up(o + (size_t)N_NODES * 4);
    int* cursor = (int*)(base + o);      o = align_up(o + (size_t)N_NODES * 4);
    float* dinv = (float*)(base + o);    o = align_up(o + (size_t)N_NODES * 4);
    int* bsum = (int*)(base + o);        o = align_up(o + 256);
    int* boff = (int*)(base + o);        o = align_up(o + 256);
    float* hfc = (float*)(base + o);     o = align_up(o + (size_t)N_NODES * D_OUT * 4);
    float* pool = (float*)(base + o);    o = align_up(o + (size_t)N_GRAPHS * D_OUT * 4);
    float* cnt = (float*)(base + o);     o = align_up(o + (size_t)N_GRAPHS * 4);

    // zero accumulators (ws is poisoned 0xAA before every call)
    hipMemsetAsync(indeg, 0, (size_t)N_NODES * 4, stream);
    hipMemsetAsync(cursor, 0, (size_t)N_NODES * 4, stream);
    hipMemsetAsync(pool, 0, (size_t)N_GRAPHS * D_OUT * 4, stream);

    // graph preprocessing
    hist_kernel<<<(N_EDGES + 255) / 256, 256, 0, stream>>>(dst, indeg);
    scan_block_sum<<<N_SCAN_BLOCKS, SCAN_B, 0, stream>>>(indeg, bsum);
    scan_partials<<<1, 64, 0, stream>>>(bsum, boff);
    scan_within<<<N_SCAN_BLOCKS, SCAN_B, 0, stream>>>(indeg, boff, row_off);
    dinv_kernel<<<(N_NODES + 255) / 256, 256, 0, stream>>>(indeg, dinv);
    fill_kernel<<<(N_EDGES + 255) / 256, 256, 0, stream>>>(src, dst, row_off, cursor, dinv,
                                                           csr_src, csr_w);

    const int gemm_grid = (N_NODES + 31) / 32;   // 1563
    const int agg_grid = (N_NODES + 3) / 4;      // 12500

    // layer 1
    gemm128<<<gemm_grid, 128, 0, stream>>>(x, W1, hW);
    agg_kernel<<<agg_grid, 256, 0, stream>>>(hW, b1, dinv, row_off, indeg, csr_src, csr_w, h);
    // layer 2
    gemm128<<<gemm_grid, 128, 0, stream>>>(h, W2, hW);
    agg_kernel<<<agg_grid, 256, 0, stream>>>(hW, b2, dinv, row_off, indeg, csr_src, csr_w, h);
    // layer 3
    gemm128<<<gemm_grid, 128, 0, stream>>>(h, W3, hW);
    agg_kernel<<<agg_grid, 256, 0, stream>>>(hW, b3, dinv, row_off, indeg, csr_src, csr_w, h);
    // layer 4
    gemm128<<<gemm_grid, 128, 0, stream>>>(h, W4, hW);
    agg_kernel<<<agg_grid, 256, 0, stream>>>(hW, b4, dinv, row_off, indeg, csr_src, csr_w, h);

    // head
    fc_kernel<<<(N_NODES + 63) / 64, 256, 0, stream>>>(h, fcW, fcb, hfc);
    pool_seg_kernel<<<POOL_BLOCKS, 256, 0, stream>>>(hfc, batch, pool);
    cnt_bs_kernel<<<1, 64, 0, stream>>>(batch, cnt);
    final_kernel<<<(N_GRAPHS * D_OUT + 255) / 256, 256, 0, stream>>>(pool, cnt, out);
}

// Round 3
// 565.778 us; speedup vs baseline: 1.8949x; 1.3779x over previous
//
#include <hip/hip_runtime.h>

// GCN: 4x GCNConv(128->128, symmetric norm, self-loops) + FC(128->32) + global mean pool.
// R2->R3: gemm rewritten as 256x64 tile, 8x8 micro, K-chunk 32, H transposed in LDS so
// A/B fragment reads are ds_read_b128 with 2-way (free) bank aliasing. R2's gemm re-read
// all 32 rows per thread per k-step -> LDS-pipe bound at 22 TF. agg: 2 edges/wave + csr
// packed as int2 (single 8B scatter/load).

#define N_NODES 50000
#define N_EDGES 600000
#define D 128
#define D_OUT 32
#define N_GRAPHS 64
#define SCAN_B 1024
#define N_SCAN_BLOCKS ((N_NODES + SCAN_B - 1) / SCAN_B)  // 49
#define POOL_L 64
#define POOL_SLOTS ((N_NODES + POOL_L - 1) / POOL_L)     // 782
#define POOL_BLOCKS ((POOL_SLOTS + 7) / 8)               // 98

// gemm tiling
#define GT_ROWS 256
#define GT_COLS 64
#define GT_KC 32
#define HS_STRIDE 260   // 256 + 4 pad (floats), mult of 4 for b128 alignment
#define WS_STRIDE 68    // 64 + 4 pad
#define N_ROWBLK ((N_NODES + GT_ROWS - 1) / GT_ROWS)  // 196

// ---------------- graph preprocessing ----------------

__global__ void hist_kernel(const int* __restrict__ dst, int* __restrict__ indeg) {
    int e = blockIdx.x * blockDim.x + threadIdx.x;
    if (e < N_EDGES) atomicAdd(&indeg[dst[e]], 1);
}

__global__ void scan_block_sum(const int* __restrict__ indeg, int* __restrict__ bsum) {
    __shared__ int sdata[SCAN_B];
    int i = blockIdx.x * SCAN_B + threadIdx.x;
    sdata[threadIdx.x] = (i < N_NODES) ? indeg[i] : 0;
    __syncthreads();
    for (int s = SCAN_B / 2; s > 0; s >>= 1) {
        if (threadIdx.x < s) sdata[threadIdx.x] += sdata[threadIdx.x + s];
        __syncthreads();
    }
    if (threadIdx.x == 0) bsum[blockIdx.x] = sdata[0];
}

__global__ void scan_partials(const int* __restrict__ bsum, int* __restrict__ boff) {
    int t = threadIdx.x;
    int orig = (t < N_SCAN_BLOCKS) ? bsum[t] : 0;
    int v = orig;
    for (int off = 1; off < 64; off <<= 1) {
        int u = __shfl_up(v, off);
        if (t >= off) v += u;
    }
    if (t < N_SCAN_BLOCKS) boff[t] = v - orig;  // exclusive
}

__global__ void scan_within(const int* __restrict__ indeg, const int* __restrict__ boff,
                            int* __restrict__ row_off) {
    __shared__ int sdata[SCAN_B];
    int i = blockIdx.x * SCAN_B + threadIdx.x;
    int orig = (i < N_NODES) ? indeg[i] : 0;
    sdata[threadIdx.x] = orig;
    __syncthreads();
    for (int off = 1; off < SCAN_B; off <<= 1) {
        int add = (threadIdx.x >= (unsigned)off) ? sdata[threadIdx.x - off] : 0;
        __syncthreads();
        if (threadIdx.x >= (unsigned)off) sdata[threadIdx.x] += add;
        __syncthreads();
    }
    if (i < N_NODES) row_off[i] = boff[blockIdx.x] + sdata[threadIdx.x] - orig;  // exclusive
}

__global__ void dinv_kernel(const int* __restrict__ indeg, float* __restrict__ dinv) {
    int i = blockIdx.x * blockDim.x + threadIdx.x;
    if (i < N_NODES) dinv[i] = rsqrtf((float)(indeg[i] + 1));  // +1 self-loop
}

__global__ void fill_kernel(const int* __restrict__ src, const int* __restrict__ dst,
                            const int* __restrict__ row_off, int* __restrict__ cursor,
                            const float* __restrict__ dinv,
                            int2* __restrict__ csr) {
    int e = blockIdx.x * blockDim.x + threadIdx.x;
    if (e >= N_EDGES) return;
    int d = dst[e], s = src[e];
    int pos = atomicAdd(&cursor[d], 1);
    int slot = row_off[d] + pos;
    csr[slot] = make_int2(s, __float_as_int(dinv[s] * dinv[d]));
}

// ---------------- dense compute ----------------

// out = H @ W, H:[N,128], W:[128,128]. Tile 256 rows x 64 cols, micro 8x8, K-chunk 32.
// HsT is k-major (transposed) so A-fragments are b128 across rows; Ws row-major so
// B-fragments are b128 across cols. Both read patterns: 8 distinct stride-8 addrs ->
// 2-way bank aliasing (free per m136).
__global__ __launch_bounds__(256) void gemm_op(const float* __restrict__ H,
                                               const float* __restrict__ W,
                                               float* __restrict__ out) {
    __shared__ float HsT[GT_KC * HS_STRIDE];  // [k][row], 33.3 KB
    __shared__ float Ws[GT_KC * WS_STRIDE];   // [k][col], 8.7 KB

    int t = threadIdx.x;
    int bid = blockIdx.x;
    int rb = bid >> 1;          // 0..195
    int cb = bid & 1;           // 0..1
    int rbase = rb * GT_ROWS;
    int cb4 = cb * (GT_COLS / 4);  // float4 col offset into out/W

    int cg = t & 7;    // 8 col-groups x 8 cols
    int rg = t >> 3;   // 32 row-groups x 8 rows

    const float4* H4 = (const float4*)H;
    const float4* W4 = (const float4*)W;

    float4 acc0[8], acc1[8];
#pragma unroll
    for (int i = 0; i < 8; ++i) {
        acc0[i] = make_float4(0.f, 0.f, 0.f, 0.f);
        acc1[i] = make_float4(0.f, 0.f, 0.f, 0.f);
    }

    for (int kc = 0; kc < 4; ++kc) {
        if (kc) __syncthreads();
        // stage H chunk (transposed): 256 rows x 8 float4
#pragma unroll
        for (int i = 0; i < 8; ++i) {
            int idx = i * 256 + t;
            int row = idx >> 3;
            int kq = idx & 7;
            int grow = rbase + row;
            float4 g = (grow < N_NODES) ? H4[grow * 32 + kc * 8 + kq]
                                        : make_float4(0.f, 0.f, 0.f, 0.f);
            HsT[(kq * 4 + 0) * HS_STRIDE + row] = g.x;
            HsT[(kq * 4 + 1) * HS_STRIDE + row] = g.y;
            HsT[(kq * 4 + 2) * HS_STRIDE + row] = g.z;
            HsT[(kq * 4 + 3) * HS_STRIDE + row] = g.w;
        }
        // stage W chunk: 32 k-rows x 16 float4
#pragma unroll
        for (int i = 0; i < 2; ++i) {
            int idx = i * 256 + t;
            int k = idx >> 4;
            int cq = idx & 15;
            float4 g = W4[(kc * GT_KC + k) * 32 + cb4 + cq];
            *(float4*)&Ws[k * WS_STRIDE + cq * 4] = g;
        }
        __syncthreads();

#pragma unroll 4
        for (int k = 0; k < GT_KC; ++k) {
            float4 a0 = *(const float4*)&HsT[k * HS_STRIDE + rg * 8];
            float4 a1 = *(const float4*)&HsT[k * HS_STRIDE + rg * 8 + 4];
            float4 b0 = *(const float4*)&Ws[k * WS_STRIDE + cg * 8];
            float4 b1 = *(const float4*)&Ws[k * WS_STRIDE + cg * 8 + 4];
            float ar[8] = {a0.x, a0.y, a0.z, a0.w, a1.x, a1.y, a1.z, a1.w};
#pragma unroll
            for (int i = 0; i < 8; ++i) {
                float ai = ar[i];
                acc0[i].x += ai * b0.x;
                acc0[i].y += ai * b0.y;
                acc0[i].z += ai * b0.z;
                acc0[i].w += ai * b0.w;
                acc1[i].x += ai * b1.x;
                acc1[i].y += ai * b1.y;
                acc1[i].z += ai * b1.z;
                acc1[i].w += ai * b1.w;
            }
        }
    }

    float4* out4 = (float4*)out;
#pragma unroll
    for (int i = 0; i < 8; ++i) {
        int row = rbase + rg * 8 + i;
        if (row < N_NODES) {
            out4[row * 32 + cb4 + cg * 2 + 0] = acc0[i];
            out4[row * 32 + cb4 + cg * 2 + 1] = acc1[i];
        }
    }
}

// One wave per node; half-wave per edge (lane = 32*half + c, float4 per lane covers the
// 512B row with 32 lanes). 2 edges in flight per trip x unroll-2 = 4 row-gathers in flight.
__global__ __launch_bounds__(256) void agg_kernel(const float* __restrict__ hW,
                                                  const float* __restrict__ bias,
                                                  const float* __restrict__ dinv,
                                                  const int* __restrict__ row_off,
                                                  const int* __restrict__ indeg,
                                                  const int2* __restrict__ csr,
                                                  float* __restrict__ out) {
    int wave = threadIdx.x >> 6;
    int lane = threadIdx.x & 63;
    int n = blockIdx.x * 4 + wave;
    if (n >= N_NODES) return;
    int half = lane >> 5;
    int c = lane & 31;
    const float4* hW4 = (const float4*)hW;

    float4 acc = make_float4(0.f, 0.f, 0.f, 0.f);
    int beg = row_off[n];
    int end = beg + indeg[n];
    int e = beg + half;
    while (e + 2 < end) {
        int2 e0 = csr[e];
        int2 e1 = csr[e + 2];
        float w0 = __int_as_float(e0.y);
        float w1 = __int_as_float(e1.y);
        float4 v0 = hW4[e0.x * 32 + c];
        float4 v1 = hW4[e1.x * 32 + c];
        acc.x += w0 * v0.x + w1 * v1.x;
        acc.y += w0 * v0.y + w1 * v1.y;
        acc.z += w0 * v0.z + w1 * v1.z;
        acc.w += w0 * v0.w + w1 * v1.w;
        e += 4;
    }
    if (e < end) {
        int2 e0 = csr[e];
        float w0 = __int_as_float(e0.y);
        float4 v0 = hW4[e0.x * 32 + c];
        acc.x += w0 * v0.x;
        acc.y += w0 * v0.y;
        acc.z += w0 * v0.z;
        acc.w += w0 * v0.w;
    }
    // combine halves
    acc.x += __shfl(acc.x, lane ^ 32);
    acc.y += __shfl(acc.y, lane ^ 32);
    acc.z += __shfl(acc.z, lane ^ 32);
    acc.w += __shfl(acc.w, lane ^ 32);
    if (half == 0) {
        float di = dinv[n];
        float sw = di * di;
        float4 hv = hW4[n * 32 + c];
        float4 b4 = ((const float4*)bias)[c];
        acc.x += b4.x + sw * hv.x;
        acc.y += b4.y + sw * hv.y;
        acc.z += b4.z + sw * hv.z;
        acc.w += b4.w + sw * hv.w;
        ((float4*)out)[n * 32 + c] = acc;
    }
}

// FC 128->32 with bias.
__global__ __launch_bounds__(256) void fc_kernel(const float* __restrict__ H,
                                                 const float* __restrict__ Wfc,
                                                 const float* __restrict__ bfc,
                                                 float* __restrict__ out) {
    __shared__ float Ws[128 * 32];
    int t = threadIdx.x;
    for (int i = 0; i < 16; ++i) Ws[i * 256 + t] = Wfc[i * 256 + t];
    __syncthreads();
    int col = t & 31, rg = t >> 5;
    int row0 = blockIdx.x * 64 + rg * 8;
    float bv = bfc[col];
    float acc[8];
#pragma unroll
    for (int r = 0; r < 8; ++r) acc[r] = bv;
    const float4* H4 = (const float4*)H;
    for (int k4 = 0; k4 < 32; ++k4) {
        float4 hv[8];
#pragma unroll
        for (int r = 0; r < 8; ++r) {
            int row = row0 + r;
            hv[r] = (row < N_NODES) ? H4[row * 32 + k4] : make_float4(0.f, 0.f, 0.f, 0.f);
        }
        float w0 = Ws[(k4 * 4 + 0) * 32 + col];
        float w1 = Ws[(k4 * 4 + 1) * 32 + col];
        float w2 = Ws[(k4 * 4 + 2) * 32 + col];
        float w3 = Ws[(k4 * 4 + 3) * 32 + col];
#pragma unroll
        for (int r = 0; r < 8; ++r)
            acc[r] += hv[r].x * w0 + hv[r].y * w1 + hv[r].z * w2 + hv[r].w * w3;
    }
    for (int r = 0; r < 8; ++r) {
        int row = row0 + r;
        if (row < N_NODES) out[row * 32 + col] = acc[r];
    }
}

// Segmented pool over SORTED batch ids.
__global__ __launch_bounds__(256) void pool_seg_kernel(const float* __restrict__ hfc,
                                                       const int* __restrict__ batch,
                                                       float* __restrict__ pool) {
    int t = threadIdx.x;
    int d = t & 31;
    int slot = blockIdx.x * 8 + (t >> 5);
    int n0 = slot * POOL_L;
    if (n0 >= N_NODES) return;
    int n1 = n0 + POOL_L;
    if (n1 > N_NODES) n1 = N_NODES;
    int gprev = batch[n0];
    float acc = 0.f;
    for (int n = n0; n < n1; ++n) {
        int g = batch[n];
        if (g != gprev) {
            atomicAdd(&pool[gprev * 32 + d], acc);
            acc = 0.f;
            gprev = g;
        }
        acc += hfc[n * 32 + d];
    }
    atomicAdd(&pool[gprev * 32 + d], acc);
}

__global__ void cnt_bs_kernel(const int* __restrict__ batch, float* __restrict__ cnt) {
    int g = threadIdx.x;
    if (g >= N_GRAPHS) return;
    int lo = 0, hi = N_NODES;
    while (lo < hi) { int mid = (lo + hi) >> 1; if (batch[mid] < g) lo = mid + 1; else hi = mid; }
    int lo2 = lo, hi2 = N_NODES;
    while (lo2 < hi2) { int mid = (lo2 + hi2) >> 1; if (batch[mid] < g + 1) lo2 = mid + 1; else hi2 = mid; }
    cnt[g] = (float)(lo2 - lo);
}

__global__ void final_kernel(const float* __restrict__ pool, const float* __restrict__ cnt,
                             float* __restrict__ out) {
    int idx = blockIdx.x * blockDim.x + threadIdx.x;
    if (idx < N_GRAPHS * D_OUT) {
        int g = idx >> 5;
        out[idx] = pool[idx] / fmaxf(cnt[g], 1.0f);
    }
}

// ---------------- launch ----------------

static inline size_t align_up(size_t x) { return (x + 255) & ~(size_t)255; }

extern "C" void kernel_launch(void* const* d_in, const int* in_sizes, int n_in,
                              void* d_out, int out_size, void* d_ws, size_t ws_size,
                              hipStream_t stream) {
    const float* x = (const float*)d_in[0];
    const int* edge_index = (const int*)d_in[1];
    const int* batch = (const int*)d_in[2];
    const float* W1 = (const float*)d_in[3];
    const float* b1 = (const float*)d_in[4];
    const float* W2 = (const float*)d_in[5];
    const float* b2 = (const float*)d_in[6];
    const float* W3 = (const float*)d_in[7];
    const float* b3 = (const float*)d_in[8];
    const float* W4 = (const float*)d_in[9];
    const float* b4 = (const float*)d_in[10];
    const float* fcW = (const float*)d_in[11];
    const float* fcb = (const float*)d_in[12];
    float* out = (float*)d_out;

    const int* src = edge_index;
    const int* dst = edge_index + N_EDGES;

    char* base = (char*)d_ws;
    size_t o = 0;
    float* hW = (float*)(base + o);      o = align_up(o + (size_t)N_NODES * D * 4);
    float* h = (float*)(base + o);       o = align_up(o + (size_t)N_NODES * D * 4);
    int2* csr = (int2*)(base + o);       o = align_up(o + (size_t)N_EDGES * 8);
    int* row_off = (int*)(base + o);     o = align_up(o + (size_t)N_NODES * 4);
    int* indeg = (int*)(base + o);       o = align_up(o + (size_t)N_NODES * 4);
    int* cursor = (int*)(base + o);      o = align_up(o + (size_t)N_NODES * 4);
    float* dinv = (float*)(base + o);    o = align_up(o + (size_t)N_NODES * 4);
    int* bsum = (int*)(base + o);        o = align_up(o + 256);
    int* boff = (int*)(base + o);        o = align_up(o + 256);
    float* hfc = (float*)(base + o);     o = align_up(o + (size_t)N_NODES * D_OUT * 4);
    float* pool = (float*)(base + o);    o = align_up(o + (size_t)N_GRAPHS * D_OUT * 4);
    float* cnt = (float*)(base + o);     o = align_up(o + (size_t)N_GRAPHS * 4);

    hipMemsetAsync(indeg, 0, (size_t)N_NODES * 4, stream);
    hipMemsetAsync(cursor, 0, (size_t)N_NODES * 4, stream);
    hipMemsetAsync(pool, 0, (size_t)N_GRAPHS * D_OUT * 4, stream);

    hist_kernel<<<(N_EDGES + 255) / 256, 256, 0, stream>>>(dst, indeg);
    scan_block_sum<<<N_SCAN_BLOCKS, SCAN_B, 0, stream>>>(indeg, bsum);
    scan_partials<<<1, 64, 0, stream>>>(bsum, boff);
    scan_within<<<N_SCAN_BLOCKS, SCAN_B, 0, stream>>>(indeg, boff, row_off);
    dinv_kernel<<<(N_NODES + 255) / 256, 256, 0, stream>>>(indeg, dinv);
    fill_kernel<<<(N_EDGES + 255) / 256, 256, 0, stream>>>(src, dst, row_off, cursor, dinv, csr);

    const int gemm_grid = N_ROWBLK * 2;          // 392
    const int agg_grid = (N_NODES + 3) / 4;      // 12500

    gemm_op<<<gemm_grid, 256, 0, stream>>>(x, W1, hW);
    agg_kernel<<<agg_grid, 256, 0, stream>>>(hW, b1, dinv, row_off, indeg, csr, h);
    gemm_op<<<gemm_grid, 256, 0, stream>>>(h, W2, hW);
    agg_kernel<<<agg_grid, 256, 0, stream>>>(hW, b2, dinv, row_off, indeg, csr, h);
    gemm_op<<<gemm_grid, 256, 0, stream>>>(h, W3, hW);
    agg_kernel<<<agg_grid, 256, 0, stream>>>(hW, b3, dinv, row_off, indeg, csr, h);
    gemm_op<<<gemm_grid, 256, 0, stream>>>(h, W4, hW);
    agg_kernel<<<agg_grid, 256, 0, stream>>>(hW, b4, dinv, row_off, indeg, csr, h);

    fc_kernel<<<(N_NODES + 63) / 64, 256, 0, stream>>>(h, fcW, fcb, hfc);
    pool_seg_kernel<<<POOL_BLOCKS, 256, 0, stream>>>(hfc, batch, pool);
    cnt_bs_kernel<<<1, 64, 0, stream>>>(batch, cnt);
    final_kernel<<<(N_GRAPHS * D_OUT + 255) / 256, 256, 0, stream>>>(pool, cnt, out);
}

// Round 4
// 493.647 us; speedup vs baseline: 2.1717x; 1.1461x over previous
//
#include <hip/hip_runtime.h>

// GCN: 4x GCNConv(128->128, sym norm, self-loops) + FC(128->32) + global mean pool.
// R3->R4: tail restructured algebraically. Everything after layer-3 agg is linear, so
//   out = mean_pool(A(h W4)+b4) fcW + fcb = mean_pool(A (h (W4 fcW))) + (b4 fcW + fcb).
// Precompute Wc=W4@fcW, bc=b4@fcW+fcb; layer 4 = gemm32 (cols=32) + agg32 (128B gathers);
// fc_kernel (50us, broadcast-load bound) deleted; bc folded into final divide.

#define N_NODES 50000
#define N_EDGES 600000
#define D 128
#define D_OUT 32
#define N_GRAPHS 64
#define SCAN_B 1024
#define N_SCAN_BLOCKS ((N_NODES + SCAN_B - 1) / SCAN_B)  // 49
#define POOL_L 64
#define POOL_SLOTS ((N_NODES + POOL_L - 1) / POOL_L)     // 782
#define POOL_BLOCKS ((POOL_SLOTS + 7) / 8)               // 98

// gemm tiling
#define GT_ROWS 256
#define GT_KC 32
#define HS_STRIDE 260   // 256 + 4 pad (floats)
#define WS_STRIDE 68    // 64 + 4 pad
#define WS2_STRIDE 36   // 32 + 4 pad
#define N_ROWBLK ((N_NODES + GT_ROWS - 1) / GT_ROWS)  // 196

// ---------------- graph preprocessing ----------------

__global__ void hist_kernel(const int* __restrict__ dst, int* __restrict__ indeg) {
    int e = blockIdx.x * blockDim.x + threadIdx.x;
    if (e < N_EDGES) atomicAdd(&indeg[dst[e]], 1);
}

__global__ void scan_block_sum(const int* __restrict__ indeg, int* __restrict__ bsum) {
    __shared__ int sdata[SCAN_B];
    int i = blockIdx.x * SCAN_B + threadIdx.x;
    sdata[threadIdx.x] = (i < N_NODES) ? indeg[i] : 0;
    __syncthreads();
    for (int s = SCAN_B / 2; s > 0; s >>= 1) {
        if (threadIdx.x < s) sdata[threadIdx.x] += sdata[threadIdx.x + s];
        __syncthreads();
    }
    if (threadIdx.x == 0) bsum[blockIdx.x] = sdata[0];
}

__global__ void scan_partials(const int* __restrict__ bsum, int* __restrict__ boff) {
    int t = threadIdx.x;
    int orig = (t < N_SCAN_BLOCKS) ? bsum[t] : 0;
    int v = orig;
    for (int off = 1; off < 64; off <<= 1) {
        int u = __shfl_up(v, off);
        if (t >= off) v += u;
    }
    if (t < N_SCAN_BLOCKS) boff[t] = v - orig;  // exclusive
}

__global__ void scan_within(const int* __restrict__ indeg, const int* __restrict__ boff,
                            int* __restrict__ row_off) {
    __shared__ int sdata[SCAN_B];
    int i = blockIdx.x * SCAN_B + threadIdx.x;
    int orig = (i < N_NODES) ? indeg[i] : 0;
    sdata[threadIdx.x] = orig;
    __syncthreads();
    for (int off = 1; off < SCAN_B; off <<= 1) {
        int add = (threadIdx.x >= (unsigned)off) ? sdata[threadIdx.x - off] : 0;
        __syncthreads();
        if (threadIdx.x >= (unsigned)off) sdata[threadIdx.x] += add;
        __syncthreads();
    }
    if (i < N_NODES) row_off[i] = boff[blockIdx.x] + sdata[threadIdx.x] - orig;  // exclusive
}

__global__ void dinv_kernel(const int* __restrict__ indeg, float* __restrict__ dinv) {
    int i = blockIdx.x * blockDim.x + threadIdx.x;
    if (i < N_NODES) dinv[i] = rsqrtf((float)(indeg[i] + 1));  // +1 self-loop
}

__global__ void fill_kernel(const int* __restrict__ src, const int* __restrict__ dst,
                            const int* __restrict__ row_off, int* __restrict__ cursor,
                            const float* __restrict__ dinv,
                            int2* __restrict__ csr) {
    int e = blockIdx.x * blockDim.x + threadIdx.x;
    if (e >= N_EDGES) return;
    int d = dst[e], s = src[e];
    int pos = atomicAdd(&cursor[d], 1);
    int slot = row_off[d] + pos;
    csr[slot] = make_int2(s, __float_as_int(dinv[s] * dinv[d]));
}

// Wc = W4 @ fcW  (128x32). 16 blocks x 8 rows; fcW staged in LDS.
__global__ __launch_bounds__(256) void wc_kernel(const float* __restrict__ W4,
                                                 const float* __restrict__ fcW,
                                                 float* __restrict__ Wc) {
    __shared__ float F[128 * 32];
    int t = threadIdx.x;
    for (int i = 0; i < 16; ++i) F[i * 256 + t] = fcW[i * 256 + t];
    __syncthreads();
    int c = t & 31, il = t >> 5;
    int i = blockIdx.x * 8 + il;
    float acc = 0.f;
    for (int k = 0; k < 128; ++k) acc += W4[i * 128 + k] * F[k * 32 + c];
    Wc[i * 32 + c] = acc;
}

// bc = b4 @ fcW + fcb  (32)
__global__ void bc_kernel(const float* __restrict__ b4, const float* __restrict__ fcW,
                          const float* __restrict__ fcb, float* __restrict__ bc) {
    int c = threadIdx.x;
    if (c >= 32) return;
    float acc = fcb[c];
    for (int k = 0; k < 128; ++k) acc += b4[k] * fcW[k * 32 + c];
    bc[c] = acc;
}

// ---------------- dense compute ----------------

// out = H @ W, H:[N,128], W:[128,128]. Tile 256x64, micro 8x8, K-chunk 32. H transposed
// in LDS -> both fragment reads are ds_read_b128, 2-way (free) bank aliasing.
__global__ __launch_bounds__(256) void gemm_op(const float* __restrict__ H,
                                               const float* __restrict__ W,
                                               float* __restrict__ out) {
    __shared__ float HsT[GT_KC * HS_STRIDE];  // [k][row], 33.3 KB
    __shared__ float Ws[GT_KC * WS_STRIDE];   // [k][col], 8.7 KB

    int t = threadIdx.x;
    int bid = blockIdx.x;
    int rb = bid >> 1;
    int cb = bid & 1;
    int rbase = rb * GT_ROWS;
    int cb4 = cb * 16;  // float4 col offset

    int cg = t & 7;
    int rg = t >> 3;

    const float4* H4 = (const float4*)H;
    const float4* W4 = (const float4*)W;

    float4 acc0[8], acc1[8];
#pragma unroll
    for (int i = 0; i < 8; ++i) {
        acc0[i] = make_float4(0.f, 0.f, 0.f, 0.f);
        acc1[i] = make_float4(0.f, 0.f, 0.f, 0.f);
    }

    for (int kc = 0; kc < 4; ++kc) {
        if (kc) __syncthreads();
#pragma unroll
        for (int i = 0; i < 8; ++i) {
            int idx = i * 256 + t;
            int row = idx >> 3;
            int kq = idx & 7;
            int grow = rbase + row;
            float4 g = (grow < N_NODES) ? H4[grow * 32 + kc * 8 + kq]
                                        : make_float4(0.f, 0.f, 0.f, 0.f);
            HsT[(kq * 4 + 0) * HS_STRIDE + row] = g.x;
            HsT[(kq * 4 + 1) * HS_STRIDE + row] = g.y;
            HsT[(kq * 4 + 2) * HS_STRIDE + row] = g.z;
            HsT[(kq * 4 + 3) * HS_STRIDE + row] = g.w;
        }
#pragma unroll
        for (int i = 0; i < 2; ++i) {
            int idx = i * 256 + t;
            int k = idx >> 4;
            int cq = idx & 15;
            float4 g = W4[(kc * GT_KC + k) * 32 + cb4 + cq];
            *(float4*)&Ws[k * WS_STRIDE + cq * 4] = g;
        }
        __syncthreads();

#pragma unroll 4
        for (int k = 0; k < GT_KC; ++k) {
            float4 a0 = *(const float4*)&HsT[k * HS_STRIDE + rg * 8];
            float4 a1 = *(const float4*)&HsT[k * HS_STRIDE + rg * 8 + 4];
            float4 b0 = *(const float4*)&Ws[k * WS_STRIDE + cg * 8];
            float4 b1 = *(const float4*)&Ws[k * WS_STRIDE + cg * 8 + 4];
            float ar[8] = {a0.x, a0.y, a0.z, a0.w, a1.x, a1.y, a1.z, a1.w};
#pragma unroll
            for (int i = 0; i < 8; ++i) {
                float ai = ar[i];
                acc0[i].x += ai * b0.x;
                acc0[i].y += ai * b0.y;
                acc0[i].z += ai * b0.z;
                acc0[i].w += ai * b0.w;
                acc1[i].x += ai * b1.x;
                acc1[i].y += ai * b1.y;
                acc1[i].z += ai * b1.z;
                acc1[i].w += ai * b1.w;
            }
        }
    }

    float4* out4 = (float4*)out;
#pragma unroll
    for (int i = 0; i < 8; ++i) {
        int row = rbase + rg * 8 + i;
        if (row < N_NODES) {
            out4[row * 32 + cb4 + cg * 2 + 0] = acc0[i];
            out4[row * 32 + cb4 + cg * 2 + 1] = acc1[i];
        }
    }
}

// G = H @ Wc, Wc:[128,32]. Tile 256 rows x 32 cols, micro 8 rows x 4 cols.
__global__ __launch_bounds__(256) void gemm32(const float* __restrict__ H,
                                              const float* __restrict__ Wc,
                                              float* __restrict__ G) {
    __shared__ float HsT[GT_KC * HS_STRIDE];
    __shared__ float Ws[GT_KC * WS2_STRIDE];

    int t = threadIdx.x;
    int rbase = blockIdx.x * GT_ROWS;
    int cg = t & 7;    // col group of 4
    int rg = t >> 3;   // 32 row groups of 8

    const float4* H4 = (const float4*)H;
    const float4* Wc4 = (const float4*)Wc;

    float4 acc[8];
#pragma unroll
    for (int i = 0; i < 8; ++i) acc[i] = make_float4(0.f, 0.f, 0.f, 0.f);

    for (int kc = 0; kc < 4; ++kc) {
        if (kc) __syncthreads();
#pragma unroll
        for (int i = 0; i < 8; ++i) {
            int idx = i * 256 + t;
            int row = idx >> 3;
            int kq = idx & 7;
            int grow = rbase + row;
            float4 g = (grow < N_NODES) ? H4[grow * 32 + kc * 8 + kq]
                                        : make_float4(0.f, 0.f, 0.f, 0.f);
            HsT[(kq * 4 + 0) * HS_STRIDE + row] = g.x;
            HsT[(kq * 4 + 1) * HS_STRIDE + row] = g.y;
            HsT[(kq * 4 + 2) * HS_STRIDE + row] = g.z;
            HsT[(kq * 4 + 3) * HS_STRIDE + row] = g.w;
        }
        {
            int k = t >> 3;       // 0..31
            int cq = t & 7;       // 0..7
            float4 g = Wc4[(kc * GT_KC + k) * 8 + cq];
            *(float4*)&Ws[k * WS2_STRIDE + cq * 4] = g;
        }
        __syncthreads();

#pragma unroll 4
        for (int k = 0; k < GT_KC; ++k) {
            float4 a0 = *(const float4*)&HsT[k * HS_STRIDE + rg * 8];
            float4 a1 = *(const float4*)&HsT[k * HS_STRIDE + rg * 8 + 4];
            float4 b0 = *(const float4*)&Ws[k * WS2_STRIDE + cg * 4];
            float ar[8] = {a0.x, a0.y, a0.z, a0.w, a1.x, a1.y, a1.z, a1.w};
#pragma unroll
            for (int i = 0; i < 8; ++i) {
                float ai = ar[i];
                acc[i].x += ai * b0.x;
                acc[i].y += ai * b0.y;
                acc[i].z += ai * b0.z;
                acc[i].w += ai * b0.w;
            }
        }
    }

    float4* G4 = (float4*)G;
#pragma unroll
    for (int i = 0; i < 8; ++i) {
        int row = rbase + rg * 8 + i;
        if (row < N_NODES) G4[row * 8 + cg] = acc[i];
    }
}

// One wave per node; half-wave per edge, float4/lane (512B rows).
__global__ __launch_bounds__(256) void agg_kernel(const float* __restrict__ hW,
                                                  const float* __restrict__ bias,
                                                  const float* __restrict__ dinv,
                                                  const int* __restrict__ row_off,
                                                  const int* __restrict__ indeg,
                                                  const int2* __restrict__ csr,
                                                  float* __restrict__ out) {
    int wave = threadIdx.x >> 6;
    int lane = threadIdx.x & 63;
    int n = blockIdx.x * 4 + wave;
    if (n >= N_NODES) return;
    int half = lane >> 5;
    int c = lane & 31;
    const float4* hW4 = (const float4*)hW;

    float4 acc = make_float4(0.f, 0.f, 0.f, 0.f);
    int beg = row_off[n];
    int end = beg + indeg[n];
    int e = beg + half;
    while (e + 2 < end) {
        int2 e0 = csr[e];
        int2 e1 = csr[e + 2];
        float w0 = __int_as_float(e0.y);
        float w1 = __int_as_float(e1.y);
        float4 v0 = hW4[e0.x * 32 + c];
        float4 v1 = hW4[e1.x * 32 + c];
        acc.x += w0 * v0.x + w1 * v1.x;
        acc.y += w0 * v0.y + w1 * v1.y;
        acc.z += w0 * v0.z + w1 * v1.z;
        acc.w += w0 * v0.w + w1 * v1.w;
        e += 4;
    }
    if (e < end) {
        int2 e0 = csr[e];
        float w0 = __int_as_float(e0.y);
        float4 v0 = hW4[e0.x * 32 + c];
        acc.x += w0 * v0.x;
        acc.y += w0 * v0.y;
        acc.z += w0 * v0.z;
        acc.w += w0 * v0.w;
    }
    acc.x += __shfl(acc.x, lane ^ 32);
    acc.y += __shfl(acc.y, lane ^ 32);
    acc.z += __shfl(acc.z, lane ^ 32);
    acc.w += __shfl(acc.w, lane ^ 32);
    if (half == 0) {
        float di = dinv[n];
        float sw = di * di;
        float4 hv = hW4[n * 32 + c];
        float4 b4 = ((const float4*)bias)[c];
        acc.x += b4.x + sw * hv.x;
        acc.y += b4.y + sw * hv.y;
        acc.z += b4.z + sw * hv.z;
        acc.w += b4.w + sw * hv.w;
        ((float4*)out)[n * 32 + c] = acc;
    }
}

// 32-dim aggregation: one wave per node, half-wave per edge, float/lane (128B rows).
// No bias (bc folded into final). p[n] = dinv^2*G[n] + sum w_e*G[src_e].
__global__ __launch_bounds__(256) void agg32_kernel(const float* __restrict__ G,
                                                    const float* __restrict__ dinv,
                                                    const int* __restrict__ row_off,
                                                    const int* __restrict__ indeg,
                                                    const int2* __restrict__ csr,
                                                    float* __restrict__ p) {
    int wave = threadIdx.x >> 6;
    int lane = threadIdx.x & 63;
    int n = blockIdx.x * 4 + wave;
    if (n >= N_NODES) return;
    int half = lane >> 5;
    int c = lane & 31;

    float acc = 0.f;
    int beg = row_off[n];
    int end = beg + indeg[n];
    int e = beg + half;
    while (e + 2 < end) {
        int2 e0 = csr[e];
        int2 e1 = csr[e + 2];
        float w0 = __int_as_float(e0.y);
        float w1 = __int_as_float(e1.y);
        acc += w0 * G[e0.x * 32 + c] + w1 * G[e1.x * 32 + c];
        e += 4;
    }
    if (e < end) {
        int2 e0 = csr[e];
        acc += __int_as_float(e0.y) * G[e0.x * 32 + c];
    }
    acc += __shfl(acc, lane ^ 32);
    if (half == 0) {
        float di = dinv[n];
        acc += di * di * G[n * 32 + c];
        p[n * 32 + c] = acc;
    }
}

// Segmented pool over SORTED batch ids.
__global__ __launch_bounds__(256) void pool_seg_kernel(const float* __restrict__ p,
                                                       const int* __restrict__ batch,
                                                       float* __restrict__ pool) {
    int t = threadIdx.x;
    int d = t & 31;
    int slot = blockIdx.x * 8 + (t >> 5);
    int n0 = slot * POOL_L;
    if (n0 >= N_NODES) return;
    int n1 = n0 + POOL_L;
    if (n1 > N_NODES) n1 = N_NODES;
    int gprev = batch[n0];
    float acc = 0.f;
    for (int n = n0; n < n1; ++n) {
        int g = batch[n];
        if (g != gprev) {
            atomicAdd(&pool[gprev * 32 + d], acc);
            acc = 0.f;
            gprev = g;
        }
        acc += p[n * 32 + d];
    }
    atomicAdd(&pool[gprev * 32 + d], acc);
}

__global__ void cnt_bs_kernel(const int* __restrict__ batch, float* __restrict__ cnt) {
    int g = threadIdx.x;
    if (g >= N_GRAPHS) return;
    int lo = 0, hi = N_NODES;
    while (lo < hi) { int mid = (lo + hi) >> 1; if (batch[mid] < g) lo = mid + 1; else hi = mid; }
    int lo2 = lo, hi2 = N_NODES;
    while (lo2 < hi2) { int mid = (lo2 + hi2) >> 1; if (batch[mid] < g + 1) lo2 = mid + 1; else hi2 = mid; }
    cnt[g] = (float)(lo2 - lo);
}

__global__ void final_kernel(const float* __restrict__ pool, const float* __restrict__ cnt,
                             const float* __restrict__ bc, float* __restrict__ out) {
    int idx = blockIdx.x * blockDim.x + threadIdx.x;
    if (idx < N_GRAPHS * D_OUT) {
        int g = idx >> 5;
        float c = cnt[g];
        out[idx] = (c > 0.f) ? pool[idx] / c + bc[idx & 31] : 0.f;
    }
}

// ---------------- launch ----------------

static inline size_t align_up(size_t x) { return (x + 255) & ~(size_t)255; }

extern "C" void kernel_launch(void* const* d_in, const int* in_sizes, int n_in,
                              void* d_out, int out_size, void* d_ws, size_t ws_size,
                              hipStream_t stream) {
    const float* x = (const float*)d_in[0];
    const int* edge_index = (const int*)d_in[1];
    const int* batch = (const int*)d_in[2];
    const float* W1 = (const float*)d_in[3];
    const float* b1 = (const float*)d_in[4];
    const float* W2 = (const float*)d_in[5];
    const float* b2 = (const float*)d_in[6];
    const float* W3 = (const float*)d_in[7];
    const float* b3 = (const float*)d_in[8];
    const float* W4 = (const float*)d_in[9];
    const float* b4 = (const float*)d_in[10];
    const float* fcW = (const float*)d_in[11];
    const float* fcb = (const float*)d_in[12];
    float* out = (float*)d_out;

    const int* src = edge_index;
    const int* dst = edge_index + N_EDGES;

    char* base = (char*)d_ws;
    size_t o = 0;
    float* hW = (float*)(base + o);      o = align_up(o + (size_t)N_NODES * D * 4);
    float* h = (float*)(base + o);       o = align_up(o + (size_t)N_NODES * D * 4);
    int2* csr = (int2*)(base + o);       o = align_up(o + (size_t)N_EDGES * 8);
    int* row_off = (int*)(base + o);     o = align_up(o + (size_t)N_NODES * 4);
    int* indeg = (int*)(base + o);       o = align_up(o + (size_t)N_NODES * 4);
    int* cursor = (int*)(base + o);      o = align_up(o + (size_t)N_NODES * 4);
    float* dinv = (float*)(base + o);    o = align_up(o + (size_t)N_NODES * 4);
    int* bsum = (int*)(base + o);        o = align_up(o + 256);
    int* boff = (int*)(base + o);        o = align_up(o + 256);
    float* pool = (float*)(base + o);    o = align_up(o + (size_t)N_GRAPHS * D_OUT * 4);
    float* cnt = (float*)(base + o);     o = align_up(o + (size_t)N_GRAPHS * 4);
    float* Wc = (float*)(base + o);      o = align_up(o + (size_t)D * D_OUT * 4);
    float* bc = (float*)(base + o);      o = align_up(o + (size_t)D_OUT * 4);
    // layer-4 tail reuses the (then-dead) hW slot: G and p are each 50000*32 floats.
    float* G = hW;
    float* p = hW + (size_t)N_NODES * D_OUT;

    hipMemsetAsync(indeg, 0, (size_t)N_NODES * 4, stream);
    hipMemsetAsync(cursor, 0, (size_t)N_NODES * 4, stream);
    hipMemsetAsync(pool, 0, (size_t)N_GRAPHS * D_OUT * 4, stream);

    hist_kernel<<<(N_EDGES + 255) / 256, 256, 0, stream>>>(dst, indeg);
    scan_block_sum<<<N_SCAN_BLOCKS, SCAN_B, 0, stream>>>(indeg, bsum);
    scan_partials<<<1, 64, 0, stream>>>(bsum, boff);
    scan_within<<<N_SCAN_BLOCKS, SCAN_B, 0, stream>>>(indeg, boff, row_off);
    dinv_kernel<<<(N_NODES + 255) / 256, 256, 0, stream>>>(indeg, dinv);
    fill_kernel<<<(N_EDGES + 255) / 256, 256, 0, stream>>>(src, dst, row_off, cursor, dinv, csr);
    wc_kernel<<<16, 256, 0, stream>>>(W4, fcW, Wc);
    bc_kernel<<<1, 32, 0, stream>>>(b4, fcW, fcb, bc);

    const int gemm_grid = N_ROWBLK * 2;          // 392
    const int agg_grid = (N_NODES + 3) / 4;      // 12500

    gemm_op<<<gemm_grid, 256, 0, stream>>>(x, W1, hW);
    agg_kernel<<<agg_grid, 256, 0, stream>>>(hW, b1, dinv, row_off, indeg, csr, h);
    gemm_op<<<gemm_grid, 256, 0, stream>>>(h, W2, hW);
    agg_kernel<<<agg_grid, 256, 0, stream>>>(hW, b2, dinv, row_off, indeg, csr, h);
    gemm_op<<<gemm_grid, 256, 0, stream>>>(h, W3, hW);
    agg_kernel<<<agg_grid, 256, 0, stream>>>(hW, b3, dinv, row_off, indeg, csr, h);
    // layer 4 + FC folded: G = h @ Wc; p = A_norm G; out = pool(p)/cnt + bc
    gemm32<<<N_ROWBLK, 256, 0, stream>>>(h, Wc, G);
    agg32_kernel<<<agg_grid, 256, 0, stream>>>(G, dinv, row_off, indeg, csr, p);

    pool_seg_kernel<<<POOL_BLOCKS, 256, 0, stream>>>(p, batch, pool);
    cnt_bs_kernel<<<1, 64, 0, stream>>>(batch, cnt);
    final_kernel<<<(N_GRAPHS * D_OUT + 255) / 256, 256, 0, stream>>>(pool, cnt, bc, out);
}

// Round 5
// 436.747 us; speedup vs baseline: 2.4547x; 1.1303x over previous
//
#include <hip/hip_runtime.h>

// GCN: 4x GCNConv(128->128, sym norm, self-loops) + FC(128->32) + global mean pool.
// R4->R5: agg was at the random-gather fetch floor for fp32 rows (FETCH 146MB vs 160MB
// per-XCD-compulsory). Only lever: fewer bytes/row -> gather operands (hW, G) stored bf16.
// GEMMs compute fp32, pack epilogue to bf16; agg gathers bf16 rows (quarter-wave/edge,
// 8 edges in flight), unpacks via shift, accumulates fp32. h stays fp32.

#define N_NODES 50000
#define N_EDGES 600000
#define D 128
#define D_OUT 32
#define N_GRAPHS 64
#define SCAN_B 1024
#define N_SCAN_BLOCKS ((N_NODES + SCAN_B - 1) / SCAN_B)  // 49
#define POOL_L 64
#define POOL_SLOTS ((N_NODES + POOL_L - 1) / POOL_L)     // 782
#define POOL_BLOCKS ((POOL_SLOTS + 7) / 8)               // 98

// gemm tiling
#define GT_ROWS 256
#define GT_KC 32
#define HS_STRIDE 260   // 256 + 4 pad (floats)
#define WS_STRIDE 68    // 64 + 4 pad
#define WS2_STRIDE 36   // 32 + 4 pad
#define N_ROWBLK ((N_NODES + GT_ROWS - 1) / GT_ROWS)  // 196

__device__ inline unsigned bf16pair(float a, float b) {
    unsigned ua = __float_as_uint(a), ub = __float_as_uint(b);
    ua = (ua + 0x7fffu + ((ua >> 16) & 1u)) >> 16;
    ub = (ub + 0x7fffu + ((ub >> 16) & 1u)) >> 16;
    return ua | (ub << 16);
}

__device__ inline void fma8(float* acc, uint4 r, float w) {
    const unsigned hm = 0xffff0000u;
    acc[0] += w * __uint_as_float(r.x << 16);
    acc[1] += w * __uint_as_float(r.x & hm);
    acc[2] += w * __uint_as_float(r.y << 16);
    acc[3] += w * __uint_as_float(r.y & hm);
    acc[4] += w * __uint_as_float(r.z << 16);
    acc[5] += w * __uint_as_float(r.z & hm);
    acc[6] += w * __uint_as_float(r.w << 16);
    acc[7] += w * __uint_as_float(r.w & hm);
}

// ---------------- graph preprocessing ----------------

__global__ void hist_kernel(const int* __restrict__ dst, int* __restrict__ indeg) {
    int e = blockIdx.x * blockDim.x + threadIdx.x;
    if (e < N_EDGES) atomicAdd(&indeg[dst[e]], 1);
}

__global__ void scan_block_sum(const int* __restrict__ indeg, int* __restrict__ bsum) {
    __shared__ int sdata[SCAN_B];
    int i = blockIdx.x * SCAN_B + threadIdx.x;
    sdata[threadIdx.x] = (i < N_NODES) ? indeg[i] : 0;
    __syncthreads();
    for (int s = SCAN_B / 2; s > 0; s >>= 1) {
        if (threadIdx.x < s) sdata[threadIdx.x] += sdata[threadIdx.x + s];
        __syncthreads();
    }
    if (threadIdx.x == 0) bsum[blockIdx.x] = sdata[0];
}

__global__ void scan_partials(const int* __restrict__ bsum, int* __restrict__ boff) {
    int t = threadIdx.x;
    int orig = (t < N_SCAN_BLOCKS) ? bsum[t] : 0;
    int v = orig;
    for (int off = 1; off < 64; off <<= 1) {
        int u = __shfl_up(v, off);
        if (t >= off) v += u;
    }
    if (t < N_SCAN_BLOCKS) boff[t] = v - orig;  // exclusive
}

__global__ void scan_within(const int* __restrict__ indeg, const int* __restrict__ boff,
                            int* __restrict__ row_off) {
    __shared__ int sdata[SCAN_B];
    int i = blockIdx.x * SCAN_B + threadIdx.x;
    int orig = (i < N_NODES) ? indeg[i] : 0;
    sdata[threadIdx.x] = orig;
    __syncthreads();
    for (int off = 1; off < SCAN_B; off <<= 1) {
        int add = (threadIdx.x >= (unsigned)off) ? sdata[threadIdx.x - off] : 0;
        __syncthreads();
        if (threadIdx.x >= (unsigned)off) sdata[threadIdx.x] += add;
        __syncthreads();
    }
    if (i < N_NODES) row_off[i] = boff[blockIdx.x] + sdata[threadIdx.x] - orig;  // exclusive
}

__global__ void dinv_kernel(const int* __restrict__ indeg, float* __restrict__ dinv) {
    int i = blockIdx.x * blockDim.x + threadIdx.x;
    if (i < N_NODES) dinv[i] = rsqrtf((float)(indeg[i] + 1));  // +1 self-loop
}

__global__ void fill_kernel(const int* __restrict__ src, const int* __restrict__ dst,
                            const int* __restrict__ row_off, int* __restrict__ cursor,
                            const float* __restrict__ dinv,
                            int2* __restrict__ csr) {
    int e = blockIdx.x * blockDim.x + threadIdx.x;
    if (e >= N_EDGES) return;
    int d = dst[e], s = src[e];
    int pos = atomicAdd(&cursor[d], 1);
    int slot = row_off[d] + pos;
    csr[slot] = make_int2(s, __float_as_int(dinv[s] * dinv[d]));
}

// Wc = W4 @ fcW  (128x32).
__global__ __launch_bounds__(256) void wc_kernel(const float* __restrict__ W4,
                                                 const float* __restrict__ fcW,
                                                 float* __restrict__ Wc) {
    __shared__ float F[128 * 32];
    int t = threadIdx.x;
    for (int i = 0; i < 16; ++i) F[i * 256 + t] = fcW[i * 256 + t];
    __syncthreads();
    int c = t & 31, il = t >> 5;
    int i = blockIdx.x * 8 + il;
    float acc = 0.f;
    for (int k = 0; k < 128; ++k) acc += W4[i * 128 + k] * F[k * 32 + c];
    Wc[i * 32 + c] = acc;
}

// bc = b4 @ fcW + fcb  (32)
__global__ void bc_kernel(const float* __restrict__ b4, const float* __restrict__ fcW,
                          const float* __restrict__ fcb, float* __restrict__ bc) {
    int c = threadIdx.x;
    if (c >= 32) return;
    float acc = fcb[c];
    for (int k = 0; k < 128; ++k) acc += b4[k] * fcW[k * 32 + c];
    bc[c] = acc;
}

// ---------------- dense compute ----------------

// out_bf16 = bf16(H @ W). H:[N,128] fp32, W:[128,128] fp32, out: bf16-packed rows.
__global__ __launch_bounds__(256) void gemm_op(const float* __restrict__ H,
                                               const float* __restrict__ W,
                                               unsigned* __restrict__ out) {
    __shared__ float HsT[GT_KC * HS_STRIDE];
    __shared__ float Ws[GT_KC * WS_STRIDE];

    int t = threadIdx.x;
    int bid = blockIdx.x;
    int rb = bid >> 1;
    int cb = bid & 1;
    int rbase = rb * GT_ROWS;
    int cb4 = cb * 16;

    int cg = t & 7;
    int rg = t >> 3;

    const float4* H4 = (const float4*)H;
    const float4* W4 = (const float4*)W;

    float4 acc0[8], acc1[8];
#pragma unroll
    for (int i = 0; i < 8; ++i) {
        acc0[i] = make_float4(0.f, 0.f, 0.f, 0.f);
        acc1[i] = make_float4(0.f, 0.f, 0.f, 0.f);
    }

    for (int kc = 0; kc < 4; ++kc) {
        if (kc) __syncthreads();
#pragma unroll
        for (int i = 0; i < 8; ++i) {
            int idx = i * 256 + t;
            int row = idx >> 3;
            int kq = idx & 7;
            int grow = rbase + row;
            float4 g = (grow < N_NODES) ? H4[grow * 32 + kc * 8 + kq]
                                        : make_float4(0.f, 0.f, 0.f, 0.f);
            HsT[(kq * 4 + 0) * HS_STRIDE + row] = g.x;
            HsT[(kq * 4 + 1) * HS_STRIDE + row] = g.y;
            HsT[(kq * 4 + 2) * HS_STRIDE + row] = g.z;
            HsT[(kq * 4 + 3) * HS_STRIDE + row] = g.w;
        }
#pragma unroll
        for (int i = 0; i < 2; ++i) {
            int idx = i * 256 + t;
            int k = idx >> 4;
            int cq = idx & 15;
            float4 g = W4[(kc * GT_KC + k) * 32 + cb4 + cq];
            *(float4*)&Ws[k * WS_STRIDE + cq * 4] = g;
        }
        __syncthreads();

#pragma unroll 4
        for (int k = 0; k < GT_KC; ++k) {
            float4 a0 = *(const float4*)&HsT[k * HS_STRIDE + rg * 8];
            float4 a1 = *(const float4*)&HsT[k * HS_STRIDE + rg * 8 + 4];
            float4 b0 = *(const float4*)&Ws[k * WS_STRIDE + cg * 8];
            float4 b1 = *(const float4*)&Ws[k * WS_STRIDE + cg * 8 + 4];
            float ar[8] = {a0.x, a0.y, a0.z, a0.w, a1.x, a1.y, a1.z, a1.w};
#pragma unroll
            for (int i = 0; i < 8; ++i) {
                float ai = ar[i];
                acc0[i].x += ai * b0.x;
                acc0[i].y += ai * b0.y;
                acc0[i].z += ai * b0.z;
                acc0[i].w += ai * b0.w;
                acc1[i].x += ai * b1.x;
                acc1[i].y += ai * b1.y;
                acc1[i].z += ai * b1.z;
                acc1[i].w += ai * b1.w;
            }
        }
    }

    uint4* out4 = (uint4*)out;  // row stride = 128 bf16 = 16 uint4
#pragma unroll
    for (int i = 0; i < 8; ++i) {
        int row = rbase + rg * 8 + i;
        if (row < N_NODES) {
            uint4 pk;
            pk.x = bf16pair(acc0[i].x, acc0[i].y);
            pk.y = bf16pair(acc0[i].z, acc0[i].w);
            pk.z = bf16pair(acc1[i].x, acc1[i].y);
            pk.w = bf16pair(acc1[i].z, acc1[i].w);
            out4[row * 16 + cb * 8 + cg] = pk;
        }
    }
}

// G_bf16 = bf16(H @ Wc), Wc:[128,32].
__global__ __launch_bounds__(256) void gemm32(const float* __restrict__ H,
                                              const float* __restrict__ Wc,
                                              unsigned* __restrict__ G) {
    __shared__ float HsT[GT_KC * HS_STRIDE];
    __shared__ float Ws[GT_KC * WS2_STRIDE];

    int t = threadIdx.x;
    int rbase = blockIdx.x * GT_ROWS;
    int cg = t & 7;
    int rg = t >> 3;

    const float4* H4 = (const float4*)H;
    const float4* Wc4 = (const float4*)Wc;

    float4 acc[8];
#pragma unroll
    for (int i = 0; i < 8; ++i) acc[i] = make_float4(0.f, 0.f, 0.f, 0.f);

    for (int kc = 0; kc < 4; ++kc) {
        if (kc) __syncthreads();
#pragma unroll
        for (int i = 0; i < 8; ++i) {
            int idx = i * 256 + t;
            int row = idx >> 3;
            int kq = idx & 7;
            int grow = rbase + row;
            float4 g = (grow < N_NODES) ? H4[grow * 32 + kc * 8 + kq]
                                        : make_float4(0.f, 0.f, 0.f, 0.f);
            HsT[(kq * 4 + 0) * HS_STRIDE + row] = g.x;
            HsT[(kq * 4 + 1) * HS_STRIDE + row] = g.y;
            HsT[(kq * 4 + 2) * HS_STRIDE + row] = g.z;
            HsT[(kq * 4 + 3) * HS_STRIDE + row] = g.w;
        }
        {
            int k = t >> 3;
            int cq = t & 7;
            float4 g = Wc4[(kc * GT_KC + k) * 8 + cq];
            *(float4*)&Ws[k * WS2_STRIDE + cq * 4] = g;
        }
        __syncthreads();

#pragma unroll 4
        for (int k = 0; k < GT_KC; ++k) {
            float4 a0 = *(const float4*)&HsT[k * HS_STRIDE + rg * 8];
            float4 a1 = *(const float4*)&HsT[k * HS_STRIDE + rg * 8 + 4];
            float4 b0 = *(const float4*)&Ws[k * WS2_STRIDE + cg * 4];
            float ar[8] = {a0.x, a0.y, a0.z, a0.w, a1.x, a1.y, a1.z, a1.w};
#pragma unroll
            for (int i = 0; i < 8; ++i) {
                float ai = ar[i];
                acc[i].x += ai * b0.x;
                acc[i].y += ai * b0.y;
                acc[i].z += ai * b0.z;
                acc[i].w += ai * b0.w;
            }
        }
    }

    uint2* G2 = (uint2*)G;  // row stride = 32 bf16 = 8 uint2
#pragma unroll
    for (int i = 0; i < 8; ++i) {
        int row = rbase + rg * 8 + i;
        if (row < N_NODES)
            G2[row * 8 + cg] = make_uint2(bf16pair(acc[i].x, acc[i].y),
                                          bf16pair(acc[i].z, acc[i].w));
    }
}

// One wave per node; quarter-wave (16 lanes) per edge, uint4/lane = 8 bf16 dims.
// 4 edges per vmem instr, unroll-2 -> 8 edges in flight per wave. fp32 accumulate.
__global__ __launch_bounds__(256) void agg_kernel(const unsigned* __restrict__ hWb,
                                                  const float* __restrict__ bias,
                                                  const float* __restrict__ dinv,
                                                  const int* __restrict__ row_off,
                                                  const int* __restrict__ indeg,
                                                  const int2* __restrict__ csr,
                                                  float* __restrict__ out) {
    int wave = threadIdx.x >> 6;
    int lane = threadIdx.x & 63;
    int n = blockIdx.x * 4 + wave;
    if (n >= N_NODES) return;
    int q = lane >> 4;   // quarter 0..3
    int c = lane & 15;   // handles dims 8c..8c+8
    const uint4* hW4 = (const uint4*)hWb;  // row = 16 uint4

    float acc[8] = {0.f, 0.f, 0.f, 0.f, 0.f, 0.f, 0.f, 0.f};
    int beg = row_off[n];
    int end = beg + indeg[n];
    int e = beg + q;
    while (e + 4 < end) {
        int2 e0 = csr[e];
        int2 e1 = csr[e + 4];
        uint4 r0 = hW4[e0.x * 16 + c];
        uint4 r1 = hW4[e1.x * 16 + c];
        fma8(acc, r0, __int_as_float(e0.y));
        fma8(acc, r1, __int_as_float(e1.y));
        e += 8;
    }
    if (e < end) {
        int2 e0 = csr[e];
        uint4 r0 = hW4[e0.x * 16 + c];
        fma8(acc, r0, __int_as_float(e0.y));
    }
#pragma unroll
    for (int i = 0; i < 8; ++i) {
        acc[i] += __shfl_xor(acc[i], 16, 64);
        acc[i] += __shfl_xor(acc[i], 32, 64);
    }
    if (q == 0) {
        float di = dinv[n];
        float sw = di * di;
        uint4 hv = hW4[n * 16 + c];
        float self[8] = {0.f, 0.f, 0.f, 0.f, 0.f, 0.f, 0.f, 0.f};
        fma8(self, hv, sw);
        float4 bA = ((const float4*)bias)[c * 2];
        float4 bB = ((const float4*)bias)[c * 2 + 1];
        float4* out4 = (float4*)out;
        out4[n * 32 + c * 2] = make_float4(acc[0] + self[0] + bA.x, acc[1] + self[1] + bA.y,
                                           acc[2] + self[2] + bA.z, acc[3] + self[3] + bA.w);
        out4[n * 32 + c * 2 + 1] = make_float4(acc[4] + self[4] + bB.x, acc[5] + self[5] + bB.y,
                                               acc[6] + self[6] + bB.z, acc[7] + self[7] + bB.w);
    }
}

// 32-dim agg on bf16 G: quarter-wave per edge, uint/lane = 2 dims. p fp32, no bias.
__global__ __launch_bounds__(256) void agg32_kernel(const unsigned* __restrict__ Gb,
                                                    const float* __restrict__ dinv,
                                                    const int* __restrict__ row_off,
                                                    const int* __restrict__ indeg,
                                                    const int2* __restrict__ csr,
                                                    float* __restrict__ p) {
    int wave = threadIdx.x >> 6;
    int lane = threadIdx.x & 63;
    int n = blockIdx.x * 4 + wave;
    if (n >= N_NODES) return;
    int q = lane >> 4;
    int c = lane & 15;  // dims 2c..2c+2

    const unsigned hm = 0xffff0000u;
    float a0 = 0.f, a1 = 0.f;
    int beg = row_off[n];
    int end = beg + indeg[n];
    int e = beg + q;
    while (e + 4 < end) {
        int2 e0 = csr[e];
        int2 e1 = csr[e + 4];
        unsigned r0 = Gb[e0.x * 16 + c];
        unsigned r1 = Gb[e1.x * 16 + c];
        float w0 = __int_as_float(e0.y), w1 = __int_as_float(e1.y);
        a0 += w0 * __uint_as_float(r0 << 16) + w1 * __uint_as_float(r1 << 16);
        a1 += w0 * __uint_as_float(r0 & hm) + w1 * __uint_as_float(r1 & hm);
        e += 8;
    }
    if (e < end) {
        int2 e0 = csr[e];
        unsigned r0 = Gb[e0.x * 16 + c];
        float w0 = __int_as_float(e0.y);
        a0 += w0 * __uint_as_float(r0 << 16);
        a1 += w0 * __uint_as_float(r0 & hm);
    }
    a0 += __shfl_xor(a0, 16, 64); a0 += __shfl_xor(a0, 32, 64);
    a1 += __shfl_xor(a1, 16, 64); a1 += __shfl_xor(a1, 32, 64);
    if (q == 0) {
        float di = dinv[n];
        float sw = di * di;
        unsigned sv = Gb[n * 16 + c];
        a0 += sw * __uint_as_float(sv << 16);
        a1 += sw * __uint_as_float(sv & hm);
        ((float2*)p)[n * 16 + c] = make_float2(a0, a1);
    }
}

// Segmented pool over SORTED batch ids.
__global__ __launch_bounds__(256) void pool_seg_kernel(const float* __restrict__ p,
                                                       const int* __restrict__ batch,
                                                       float* __restrict__ pool) {
    int t = threadIdx.x;
    int d = t & 31;
    int slot = blockIdx.x * 8 + (t >> 5);
    int n0 = slot * POOL_L;
    if (n0 >= N_NODES) return;
    int n1 = n0 + POOL_L;
    if (n1 > N_NODES) n1 = N_NODES;
    int gprev = batch[n0];
    float acc = 0.f;
    for (int n = n0; n < n1; ++n) {
        int g = batch[n];
        if (g != gprev) {
            atomicAdd(&pool[gprev * 32 + d], acc);
            acc = 0.f;
            gprev = g;
        }
        acc += p[n * 32 + d];
    }
    atomicAdd(&pool[gprev * 32 + d], acc);
}

__global__ void cnt_bs_kernel(const int* __restrict__ batch, float* __restrict__ cnt) {
    int g = threadIdx.x;
    if (g >= N_GRAPHS) return;
    int lo = 0, hi = N_NODES;
    while (lo < hi) { int mid = (lo + hi) >> 1; if (batch[mid] < g) lo = mid + 1; else hi = mid; }
    int lo2 = lo, hi2 = N_NODES;
    while (lo2 < hi2) { int mid = (lo2 + hi2) >> 1; if (batch[mid] < g + 1) lo2 = mid + 1; else hi2 = mid; }
    cnt[g] = (float)(lo2 - lo);
}

__global__ void final_kernel(const float* __restrict__ pool, const float* __restrict__ cnt,
                             const float* __restrict__ bc, float* __restrict__ out) {
    int idx = blockIdx.x * blockDim.x + threadIdx.x;
    if (idx < N_GRAPHS * D_OUT) {
        int g = idx >> 5;
        float c = cnt[g];
        out[idx] = (c > 0.f) ? pool[idx] / c + bc[idx & 31] : 0.f;
    }
}

// ---------------- launch ----------------

static inline size_t align_up(size_t x) { return (x + 255) & ~(size_t)255; }

extern "C" void kernel_launch(void* const* d_in, const int* in_sizes, int n_in,
                              void* d_out, int out_size, void* d_ws, size_t ws_size,
                              hipStream_t stream) {
    const float* x = (const float*)d_in[0];
    const int* edge_index = (const int*)d_in[1];
    const int* batch = (const int*)d_in[2];
    const float* W1 = (const float*)d_in[3];
    const float* b1 = (const float*)d_in[4];
    const float* W2 = (const float*)d_in[5];
    const float* b2 = (const float*)d_in[6];
    const float* W3 = (const float*)d_in[7];
    const float* b3 = (const float*)d_in[8];
    const float* W4 = (const float*)d_in[9];
    const float* b4 = (const float*)d_in[10];
    const float* fcW = (const float*)d_in[11];
    const float* fcb = (const float*)d_in[12];
    float* out = (float*)d_out;

    const int* src = edge_index;
    const int* dst = edge_index + N_EDGES;

    char* base = (char*)d_ws;
    size_t o = 0;
    unsigned* hWb = (unsigned*)(base + o); o = align_up(o + (size_t)N_NODES * D * 2);  // bf16
    float* h = (float*)(base + o);       o = align_up(o + (size_t)N_NODES * D * 4);
    int2* csr = (int2*)(base + o);       o = align_up(o + (size_t)N_EDGES * 8);
    int* row_off = (int*)(base + o);     o = align_up(o + (size_t)N_NODES * 4);
    int* indeg = (int*)(base + o);       o = align_up(o + (size_t)N_NODES * 4);
    int* cursor = (int*)(base + o);      o = align_up(o + (size_t)N_NODES * 4);
    float* dinv = (float*)(base + o);    o = align_up(o + (size_t)N_NODES * 4);
    int* bsum = (int*)(base + o);        o = align_up(o + 256);
    int* boff = (int*)(base + o);        o = align_up(o + 256);
    float* pool = (float*)(base + o);    o = align_up(o + (size_t)N_GRAPHS * D_OUT * 4);
    float* cnt = (float*)(base + o);     o = align_up(o + (size_t)N_GRAPHS * 4);
    float* Wc = (float*)(base + o);      o = align_up(o + (size_t)D * D_OUT * 4);
    float* bc = (float*)(base + o);      o = align_up(o + (size_t)D_OUT * 4);
    float* p = (float*)(base + o);       o = align_up(o + (size_t)N_NODES * D_OUT * 4);
    // layer-4 G (bf16, 3.2MB) reuses the then-dead hWb slot (12.8MB)
    unsigned* Gb = hWb;

    hipMemsetAsync(indeg, 0, (size_t)N_NODES * 4, stream);
    hipMemsetAsync(cursor, 0, (size_t)N_NODES * 4, stream);
    hipMemsetAsync(pool, 0, (size_t)N_GRAPHS * D_OUT * 4, stream);

    hist_kernel<<<(N_EDGES + 255) / 256, 256, 0, stream>>>(dst, indeg);
    scan_block_sum<<<N_SCAN_BLOCKS, SCAN_B, 0, stream>>>(indeg, bsum);
    scan_partials<<<1, 64, 0, stream>>>(bsum, boff);
    scan_within<<<N_SCAN_BLOCKS, SCAN_B, 0, stream>>>(indeg, boff, row_off);
    dinv_kernel<<<(N_NODES + 255) / 256, 256, 0, stream>>>(indeg, dinv);
    fill_kernel<<<(N_EDGES + 255) / 256, 256, 0, stream>>>(src, dst, row_off, cursor, dinv, csr);
    wc_kernel<<<16, 256, 0, stream>>>(W4, fcW, Wc);
    bc_kernel<<<1, 32, 0, stream>>>(b4, fcW, fcb, bc);

    const int gemm_grid = N_ROWBLK * 2;          // 392
    const int agg_grid = (N_NODES + 3) / 4;      // 12500

    gemm_op<<<gemm_grid, 256, 0, stream>>>(x, W1, hWb);
    agg_kernel<<<agg_grid, 256, 0, stream>>>(hWb, b1, dinv, row_off, indeg, csr, h);
    gemm_op<<<gemm_grid, 256, 0, stream>>>(h, W2, hWb);
    agg_kernel<<<agg_grid, 256, 0, stream>>>(hWb, b2, dinv, row_off, indeg, csr, h);
    gemm_op<<<gemm_grid, 256, 0, stream>>>(h, W3, hWb);
    agg_kernel<<<agg_grid, 256, 0, stream>>>(hWb, b3, dinv, row_off, indeg, csr, h);
    // layer 4 + FC folded
    gemm32<<<N_ROWBLK, 256, 0, stream>>>(h, Wc, Gb);
    agg32_kernel<<<agg_grid, 256, 0, stream>>>(Gb, dinv, row_off, indeg, csr, p);

    pool_seg_kernel<<<POOL_BLOCKS, 256, 0, stream>>>(p, batch, pool);
    cnt_bs_kernel<<<1, 64, 0, stream>>>(batch, cnt);
    final_kernel<<<(N_GRAPHS * D_OUT + 255) / 256, 256, 0, stream>>>(pool, cnt, bc, out);
}

// Round 6
// 398.088 us; speedup vs baseline: 2.6931x; 1.0971x over previous
//
#include <hip/hip_runtime.h>

// GCN: 4x GCNConv(128->128, sym norm, self-loops) + FC(128->32) + global mean pool.
// R5->R6: GEMMs moved to MFMA bf16 (16x16x32). h/x/W stored bf16; per wave 16 rows x
// full width, A-frags direct from global (64B-coalesced), B-frags from pre-transposed
// WT (32KB, L1-resident) -> no LDS staging, no K-loop barriers. Epilogue: D-layout ->
// row-major bf16 via per-wave LDS tile. agg unchanged (R5-verified) except bf16 h out.

#define N_NODES 50000
#define N_EDGES 600000
#define D 128
#define D_OUT 32
#define N_GRAPHS 64
#define SCAN_B 1024
#define N_SCAN_BLOCKS ((N_NODES + SCAN_B - 1) / SCAN_B)  // 49
#define POOL_L 64
#define POOL_SLOTS ((N_NODES + POOL_L - 1) / POOL_L)     // 782
#define POOL_BLOCKS ((POOL_SLOTS + 7) / 8)               // 98
#define GEMM_BLOCKS ((N_NODES + 63) / 64)                // 782

typedef short short8 __attribute__((ext_vector_type(8)));
typedef float floatx4 __attribute__((ext_vector_type(4)));

__device__ inline unsigned bf16rne(float a) {
    unsigned u = __float_as_uint(a);
    return (u + 0x7fffu + ((u >> 16) & 1u)) >> 16;
}
__device__ inline unsigned bf16pair(float a, float b) {
    return bf16rne(a) | (bf16rne(b) << 16);
}
__device__ inline void fma8(float* acc, uint4 r, float w) {
    const unsigned hm = 0xffff0000u;
    acc[0] += w * __uint_as_float(r.x << 16);
    acc[1] += w * __uint_as_float(r.x & hm);
    acc[2] += w * __uint_as_float(r.y << 16);
    acc[3] += w * __uint_as_float(r.y & hm);
    acc[4] += w * __uint_as_float(r.z << 16);
    acc[5] += w * __uint_as_float(r.z & hm);
    acc[6] += w * __uint_as_float(r.w << 16);
    acc[7] += w * __uint_as_float(r.w & hm);
}

// ---------------- graph preprocessing ----------------

__global__ void hist_kernel(const int* __restrict__ dst, int* __restrict__ indeg) {
    int e = blockIdx.x * blockDim.x + threadIdx.x;
    if (e < N_EDGES) atomicAdd(&indeg[dst[e]], 1);
}

__global__ void scan_block_sum(const int* __restrict__ indeg, int* __restrict__ bsum) {
    __shared__ int sdata[SCAN_B];
    int i = blockIdx.x * SCAN_B + threadIdx.x;
    sdata[threadIdx.x] = (i < N_NODES) ? indeg[i] : 0;
    __syncthreads();
    for (int s = SCAN_B / 2; s > 0; s >>= 1) {
        if (threadIdx.x < s) sdata[threadIdx.x] += sdata[threadIdx.x + s];
        __syncthreads();
    }
    if (threadIdx.x == 0) bsum[blockIdx.x] = sdata[0];
}

__global__ void scan_partials(const int* __restrict__ bsum, int* __restrict__ boff) {
    int t = threadIdx.x;
    int orig = (t < N_SCAN_BLOCKS) ? bsum[t] : 0;
    int v = orig;
    for (int off = 1; off < 64; off <<= 1) {
        int u = __shfl_up(v, off);
        if (t >= off) v += u;
    }
    if (t < N_SCAN_BLOCKS) boff[t] = v - orig;  // exclusive
}

__global__ void scan_within(const int* __restrict__ indeg, const int* __restrict__ boff,
                            int* __restrict__ row_off) {
    __shared__ int sdata[SCAN_B];
    int i = blockIdx.x * SCAN_B + threadIdx.x;
    int orig = (i < N_NODES) ? indeg[i] : 0;
    sdata[threadIdx.x] = orig;
    __syncthreads();
    for (int off = 1; off < SCAN_B; off <<= 1) {
        int add = (threadIdx.x >= (unsigned)off) ? sdata[threadIdx.x - off] : 0;
        __syncthreads();
        if (threadIdx.x >= (unsigned)off) sdata[threadIdx.x] += add;
        __syncthreads();
    }
    if (i < N_NODES) row_off[i] = boff[blockIdx.x] + sdata[threadIdx.x] - orig;  // exclusive
}

__global__ void dinv_kernel(const int* __restrict__ indeg, float* __restrict__ dinv) {
    int i = blockIdx.x * blockDim.x + threadIdx.x;
    if (i < N_NODES) dinv[i] = rsqrtf((float)(indeg[i] + 1));  // +1 self-loop
}

__global__ void fill_kernel(const int* __restrict__ src, const int* __restrict__ dst,
                            const int* __restrict__ row_off, int* __restrict__ cursor,
                            const float* __restrict__ dinv,
                            int2* __restrict__ csr) {
    int e = blockIdx.x * blockDim.x + threadIdx.x;
    if (e >= N_EDGES) return;
    int d = dst[e], s = src[e];
    int pos = atomicAdd(&cursor[d], 1);
    int slot = row_off[d] + pos;
    csr[slot] = make_int2(s, __float_as_int(dinv[s] * dinv[d]));
}

// x fp32 -> bf16 packed. 8 elems/thread.
__global__ void x2b_kernel(const float* __restrict__ x, unsigned* __restrict__ xb) {
    int i = blockIdx.x * blockDim.x + threadIdx.x;  // uint4 index, N*128/8 total
    const float4* x4 = (const float4*)x;
    float4 a = x4[i * 2], b = x4[i * 2 + 1];
    ((uint4*)xb)[i] = make_uint4(bf16pair(a.x, a.y), bf16pair(a.z, a.w),
                                 bf16pair(b.x, b.y), bf16pair(b.z, b.w));
}

// Transpose W (fp32 [128][128]) -> WT (bf16, WT[n][k]=W[k][n]). One block per W.
__global__ __launch_bounds__(256) void wt_kernel(const float* __restrict__ W1,
                                                 const float* __restrict__ W2,
                                                 const float* __restrict__ W3,
                                                 unsigned* __restrict__ WT1,
                                                 unsigned* __restrict__ WT2,
                                                 unsigned* __restrict__ WT3) {
    __shared__ float Lf[128 * 128];
    const float* W = (blockIdx.x == 0) ? W1 : (blockIdx.x == 1) ? W2 : W3;
    unsigned* WT = (blockIdx.x == 0) ? WT1 : (blockIdx.x == 1) ? WT2 : WT3;
    int t = threadIdx.x;
    const float4* W4 = (const float4*)W;
    float4* L4 = (float4*)Lf;
    for (int i = 0; i < 16; ++i) L4[i * 256 + t] = W4[i * 256 + t];
    __syncthreads();
    int n = t >> 1, hf = t & 1;
    uint4* WT4 = (uint4*)WT;
    for (int i = 0; i < 8; ++i) {
        int k0 = hf * 64 + i * 8;
        uint4 pk;
        pk.x = bf16pair(Lf[(k0 + 0) * 128 + n], Lf[(k0 + 1) * 128 + n]);
        pk.y = bf16pair(Lf[(k0 + 2) * 128 + n], Lf[(k0 + 3) * 128 + n]);
        pk.z = bf16pair(Lf[(k0 + 4) * 128 + n], Lf[(k0 + 5) * 128 + n]);
        pk.w = bf16pair(Lf[(k0 + 6) * 128 + n], Lf[(k0 + 7) * 128 + n]);
        WT4[n * 16 + hf * 8 + i] = pk;
    }
}

// WcT[c][k] = bf16( (W4 @ fcW)[k][c] ), c in [0,32), k in [0,128).
__global__ __launch_bounds__(256) void wc_kernel(const float* __restrict__ W4,
                                                 const float* __restrict__ fcW,
                                                 unsigned short* __restrict__ WcT) {
    __shared__ float F[128 * 32];
    int t = threadIdx.x;
    for (int i = 0; i < 16; ++i) F[i * 256 + t] = fcW[i * 256 + t];
    __syncthreads();
    int c = t & 31, il = t >> 5;
    int i = blockIdx.x * 8 + il;  // k index
    float acc = 0.f;
    for (int k = 0; k < 128; ++k) acc += W4[i * 128 + k] * F[k * 32 + c];
    WcT[c * 128 + i] = (unsigned short)bf16rne(acc);
}

// bc = b4 @ fcW + fcb  (32)
__global__ void bc_kernel(const float* __restrict__ b4, const float* __restrict__ fcW,
                          const float* __restrict__ fcb, float* __restrict__ bc) {
    int c = threadIdx.x;
    if (c >= 32) return;
    float acc = fcb[c];
    for (int k = 0; k < 128; ++k) acc += b4[k] * fcW[k * 32 + c];
    bc[c] = acc;
}

// ---------------- MFMA GEMMs ----------------

// out = bf16(A @ W): A [N][128] bf16, WT [128][128] bf16 (WT[n][k]), out bf16 rows.
// Wave: 16 rows x 128 cols, K=128 -> 8 col-tiles x 4 MFMAs. No K-loop LDS/barriers.
__global__ __launch_bounds__(256) void gemm_mfma(const unsigned short* __restrict__ Ab,
                                                 const unsigned short* __restrict__ WT,
                                                 uint4* __restrict__ outb) {
    __shared__ unsigned short tile[4][16 * 136];
    int t = threadIdx.x;
    int wave = t >> 6, lane = t & 63;
    int row0 = blockIdx.x * 64 + wave * 16;
    int lm = lane & 15, lg = lane >> 4;

    int arow = row0 + lm;
    if (arow >= N_NODES) arow = N_NODES - 1;
    const short8* Arow = (const short8*)(Ab + (size_t)arow * 128);
    short8 a[4];
#pragma unroll
    for (int kc = 0; kc < 4; ++kc) a[kc] = Arow[kc * 4 + lg];

    floatx4 acc[8];
#pragma unroll
    for (int i = 0; i < 8; ++i) acc[i] = (floatx4){0.f, 0.f, 0.f, 0.f};

#pragma unroll
    for (int nt = 0; nt < 8; ++nt) {
        const short8* Brow = (const short8*)(WT + (size_t)(nt * 16 + lm) * 128);
#pragma unroll
        for (int kc = 0; kc < 4; ++kc) {
            short8 b = Brow[kc * 4 + lg];
            acc[nt] = __builtin_amdgcn_mfma_f32_16x16x32_bf16(a[kc], b, acc[nt], 0, 0, 0);
        }
    }

    // D layout: row=(lane>>4)*4+r, col=nt*16+(lane&15) -> row-major bf16 via LDS
    unsigned short* T = tile[wave];
#pragma unroll
    for (int nt = 0; nt < 8; ++nt)
#pragma unroll
        for (int r = 0; r < 4; ++r)
            T[(lg * 4 + r) * 136 + nt * 16 + lm] = (unsigned short)bf16rne(acc[nt][r]);
    __syncthreads();
    int rr = lane >> 2, cseg = lane & 3;
    int orow = row0 + rr;
#pragma unroll
    for (int it = 0; it < 4; ++it) {
        uint4 v = *(const uint4*)&T[rr * 136 + cseg * 8 + it * 32];
        if (orow < N_NODES) outb[(size_t)orow * 16 + it * 4 + cseg] = v;
    }
}

// G = bf16(A @ Wc): WcT [32][128] bf16, out [N][32] bf16.
__global__ __launch_bounds__(256) void gemm32_mfma(const unsigned short* __restrict__ Ab,
                                                   const unsigned short* __restrict__ WcT,
                                                   uint4* __restrict__ outb) {
    __shared__ unsigned short tile[4][16 * 32];
    int t = threadIdx.x;
    int wave = t >> 6, lane = t & 63;
    int row0 = blockIdx.x * 64 + wave * 16;
    int lm = lane & 15, lg = lane >> 4;

    int arow = row0 + lm;
    if (arow >= N_NODES) arow = N_NODES - 1;
    const short8* Arow = (const short8*)(Ab + (size_t)arow * 128);
    short8 a[4];
#pragma unroll
    for (int kc = 0; kc < 4; ++kc) a[kc] = Arow[kc * 4 + lg];

    floatx4 acc[2];
#pragma unroll
    for (int i = 0; i < 2; ++i) acc[i] = (floatx4){0.f, 0.f, 0.f, 0.f};

#pragma unroll
    for (int nt = 0; nt < 2; ++nt) {
        const short8* Brow = (const short8*)(WcT + (size_t)(nt * 16 + lm) * 128);
#pragma unroll
        for (int kc = 0; kc < 4; ++kc) {
            short8 b = Brow[kc * 4 + lg];
            acc[nt] = __builtin_amdgcn_mfma_f32_16x16x32_bf16(a[kc], b, acc[nt], 0, 0, 0);
        }
    }

    unsigned short* T = tile[wave];
#pragma unroll
    for (int nt = 0; nt < 2; ++nt)
#pragma unroll
        for (int r = 0; r < 4; ++r)
            T[(lg * 4 + r) * 32 + nt * 16 + lm] = (unsigned short)bf16rne(acc[nt][r]);
    __syncthreads();
    int rr = lane >> 2, cseg = lane & 3;
    int orow = row0 + rr;
    uint4 v = *(const uint4*)&T[rr * 32 + cseg * 8];
    if (orow < N_NODES) outb[(size_t)orow * 4 + cseg] = v;
}

// ---------------- aggregation (R5-verified structure) ----------------

// One wave/node; quarter-wave (16 lanes)/edge, uint4/lane = 8 bf16 dims. Output bf16 row.
__global__ __launch_bounds__(256) void agg_kernel(const unsigned* __restrict__ hWb,
                                                  const float* __restrict__ bias,
                                                  const float* __restrict__ dinv,
                                                  const int* __restrict__ row_off,
                                                  const int* __restrict__ indeg,
                                                  const int2* __restrict__ csr,
                                                  uint4* __restrict__ outb) {
    int wave = threadIdx.x >> 6;
    int lane = threadIdx.x & 63;
    int n = blockIdx.x * 4 + wave;
    if (n >= N_NODES) return;
    int q = lane >> 4;
    int c = lane & 15;
    const uint4* hW4 = (const uint4*)hWb;

    float acc[8] = {0.f, 0.f, 0.f, 0.f, 0.f, 0.f, 0.f, 0.f};
    int beg = row_off[n];
    int end = beg + indeg[n];
    int e = beg + q;
    while (e + 4 < end) {
        int2 e0 = csr[e];
        int2 e1 = csr[e + 4];
        uint4 r0 = hW4[e0.x * 16 + c];
        uint4 r1 = hW4[e1.x * 16 + c];
        fma8(acc, r0, __int_as_float(e0.y));
        fma8(acc, r1, __int_as_float(e1.y));
        e += 8;
    }
    if (e < end) {
        int2 e0 = csr[e];
        uint4 r0 = hW4[e0.x * 16 + c];
        fma8(acc, r0, __int_as_float(e0.y));
    }
#pragma unroll
    for (int i = 0; i < 8; ++i) {
        acc[i] += __shfl_xor(acc[i], 16, 64);
        acc[i] += __shfl_xor(acc[i], 32, 64);
    }
    if (q == 0) {
        float di = dinv[n];
        float sw = di * di;
        uint4 hv = hW4[n * 16 + c];
        fma8(acc, hv, sw);
        float4 bA = ((const float4*)bias)[c * 2];
        float4 bB = ((const float4*)bias)[c * 2 + 1];
        uint4 pk;
        pk.x = bf16pair(acc[0] + bA.x, acc[1] + bA.y);
        pk.y = bf16pair(acc[2] + bA.z, acc[3] + bA.w);
        pk.z = bf16pair(acc[4] + bB.x, acc[5] + bB.y);
        pk.w = bf16pair(acc[6] + bB.z, acc[7] + bB.w);
        outb[(size_t)n * 16 + c] = pk;
    }
}

// 32-dim agg on bf16 G -> p fp32 (no bias).
__global__ __launch_bounds__(256) void agg32_kernel(const unsigned* __restrict__ Gb,
                                                    const float* __restrict__ dinv,
                                                    const int* __restrict__ row_off,
                                                    const int* __restrict__ indeg,
                                                    const int2* __restrict__ csr,
                                                    float* __restrict__ p) {
    int wave = threadIdx.x >> 6;
    int lane = threadIdx.x & 63;
    int n = blockIdx.x * 4 + wave;
    if (n >= N_NODES) return;
    int q = lane >> 4;
    int c = lane & 15;

    const unsigned hm = 0xffff0000u;
    float a0 = 0.f, a1 = 0.f;
    int beg = row_off[n];
    int end = beg + indeg[n];
    int e = beg + q;
    while (e + 4 < end) {
        int2 e0 = csr[e];
        int2 e1 = csr[e + 4];
        unsigned r0 = Gb[e0.x * 16 + c];
        unsigned r1 = Gb[e1.x * 16 + c];
        float w0 = __int_as_float(e0.y), w1 = __int_as_float(e1.y);
        a0 += w0 * __uint_as_float(r0 << 16) + w1 * __uint_as_float(r1 << 16);
        a1 += w0 * __uint_as_float(r0 & hm) + w1 * __uint_as_float(r1 & hm);
        e += 8;
    }
    if (e < end) {
        int2 e0 = csr[e];
        unsigned r0 = Gb[e0.x * 16 + c];
        float w0 = __int_as_float(e0.y);
        a0 += w0 * __uint_as_float(r0 << 16);
        a1 += w0 * __uint_as_float(r0 & hm);
    }
    a0 += __shfl_xor(a0, 16, 64); a0 += __shfl_xor(a0, 32, 64);
    a1 += __shfl_xor(a1, 16, 64); a1 += __shfl_xor(a1, 32, 64);
    if (q == 0) {
        float di = dinv[n];
        float sw = di * di;
        unsigned sv = Gb[n * 16 + c];
        a0 += sw * __uint_as_float(sv << 16);
        a1 += sw * __uint_as_float(sv & hm);
        ((float2*)p)[n * 16 + c] = make_float2(a0, a1);
    }
}

// Segmented pool over SORTED batch ids.
__global__ __launch_bounds__(256) void pool_seg_kernel(const float* __restrict__ p,
                                                       const int* __restrict__ batch,
                                                       float* __restrict__ pool) {
    int t = threadIdx.x;
    int d = t & 31;
    int slot = blockIdx.x * 8 + (t >> 5);
    int n0 = slot * POOL_L;
    if (n0 >= N_NODES) return;
    int n1 = n0 + POOL_L;
    if (n1 > N_NODES) n1 = N_NODES;
    int gprev = batch[n0];
    float acc = 0.f;
    for (int n = n0; n < n1; ++n) {
        int g = batch[n];
        if (g != gprev) {
            atomicAdd(&pool[gprev * 32 + d], acc);
            acc = 0.f;
            gprev = g;
        }
        acc += p[n * 32 + d];
    }
    atomicAdd(&pool[gprev * 32 + d], acc);
}

__global__ void cnt_bs_kernel(const int* __restrict__ batch, float* __restrict__ cnt) {
    int g = threadIdx.x;
    if (g >= N_GRAPHS) return;
    int lo = 0, hi = N_NODES;
    while (lo < hi) { int mid = (lo + hi) >> 1; if (batch[mid] < g) lo = mid + 1; else hi = mid; }
    int lo2 = lo, hi2 = N_NODES;
    while (lo2 < hi2) { int mid = (lo2 + hi2) >> 1; if (batch[mid] < g + 1) lo2 = mid + 1; else hi2 = mid; }
    cnt[g] = (float)(lo2 - lo);
}

__global__ void final_kernel(const float* __restrict__ pool, const float* __restrict__ cnt,
                             const float* __restrict__ bc, float* __restrict__ out) {
    int idx = blockIdx.x * blockDim.x + threadIdx.x;
    if (idx < N_GRAPHS * D_OUT) {
        int g = idx >> 5;
        float c = cnt[g];
        out[idx] = (c > 0.f) ? pool[idx] / c + bc[idx & 31] : 0.f;
    }
}

// ---------------- launch ----------------

static inline size_t align_up(size_t x) { return (x + 255) & ~(size_t)255; }

extern "C" void kernel_launch(void* const* d_in, const int* in_sizes, int n_in,
                              void* d_out, int out_size, void* d_ws, size_t ws_size,
                              hipStream_t stream) {
    const float* x = (const float*)d_in[0];
    const int* edge_index = (const int*)d_in[1];
    const int* batch = (const int*)d_in[2];
    const float* W1 = (const float*)d_in[3];
    const float* b1 = (const float*)d_in[4];
    const float* W2 = (const float*)d_in[5];
    const float* b2 = (const float*)d_in[6];
    const float* W3 = (const float*)d_in[7];
    const float* b3 = (const float*)d_in[8];
    const float* W4 = (const float*)d_in[9];
    const float* b4 = (const float*)d_in[10];
    const float* fcW = (const float*)d_in[11];
    const float* fcb = (const float*)d_in[12];
    float* out = (float*)d_out;

    const int* src = edge_index;
    const int* dst = edge_index + N_EDGES;

    char* base = (char*)d_ws;
    size_t o = 0;
    unsigned* xb = (unsigned*)(base + o);   o = align_up(o + (size_t)N_NODES * D * 2);
    unsigned* hWb = (unsigned*)(base + o);  o = align_up(o + (size_t)N_NODES * D * 2);
    unsigned* hb = (unsigned*)(base + o);   o = align_up(o + (size_t)N_NODES * D * 2);
    int2* csr = (int2*)(base + o);          o = align_up(o + (size_t)N_EDGES * 8);
    int* row_off = (int*)(base + o);        o = align_up(o + (size_t)N_NODES * 4);
    int* indeg = (int*)(base + o);          o = align_up(o + (size_t)N_NODES * 4);
    int* cursor = (int*)(base + o);         o = align_up(o + (size_t)N_NODES * 4);
    float* dinv = (float*)(base + o);       o = align_up(o + (size_t)N_NODES * 4);
    int* bsum = (int*)(base + o);           o = align_up(o + 256);
    int* boff = (int*)(base + o);           o = align_up(o + 256);
    float* pool = (float*)(base + o);       o = align_up(o + (size_t)N_GRAPHS * D_OUT * 4);
    float* cnt = (float*)(base + o);        o = align_up(o + (size_t)N_GRAPHS * 4);
    unsigned* WT1 = (unsigned*)(base + o);  o = align_up(o + (size_t)D * D * 2);
    unsigned* WT2 = (unsigned*)(base + o);  o = align_up(o + (size_t)D * D * 2);
    unsigned* WT3 = (unsigned*)(base + o);  o = align_up(o + (size_t)D * D * 2);
    unsigned short* WcT = (unsigned short*)(base + o); o = align_up(o + (size_t)D * D_OUT * 2);
    float* bc = (float*)(base + o);         o = align_up(o + (size_t)D_OUT * 4);
    float* p = (float*)(base + o);          o = align_up(o + (size_t)N_NODES * D_OUT * 4);
    unsigned* Gb = hWb;  // layer-4 G (bf16) reuses dead hWb slot

    hipMemsetAsync(indeg, 0, (size_t)N_NODES * 4, stream);
    hipMemsetAsync(cursor, 0, (size_t)N_NODES * 4, stream);
    hipMemsetAsync(pool, 0, (size_t)N_GRAPHS * D_OUT * 4, stream);

    hist_kernel<<<(N_EDGES + 255) / 256, 256, 0, stream>>>(dst, indeg);
    scan_block_sum<<<N_SCAN_BLOCKS, SCAN_B, 0, stream>>>(indeg, bsum);
    scan_partials<<<1, 64, 0, stream>>>(bsum, boff);
    scan_within<<<N_SCAN_BLOCKS, SCAN_B, 0, stream>>>(indeg, boff, row_off);
    dinv_kernel<<<(N_NODES + 255) / 256, 256, 0, stream>>>(indeg, dinv);
    fill_kernel<<<(N_EDGES + 255) / 256, 256, 0, stream>>>(src, dst, row_off, cursor, dinv, csr);
    wt_kernel<<<3, 256, 0, stream>>>(W1, W2, W3, WT1, WT2, WT3);
    wc_kernel<<<16, 256, 0, stream>>>(W4, fcW, WcT);
    bc_kernel<<<1, 32, 0, stream>>>(b4, fcW, fcb, bc);
    x2b_kernel<<<(N_NODES * D / 8 + 255) / 256, 256, 0, stream>>>(x, xb);

    const int agg_grid = (N_NODES + 3) / 4;  // 12500

    gemm_mfma<<<GEMM_BLOCKS, 256, 0, stream>>>((const unsigned short*)xb,
                                               (const unsigned short*)WT1, (uint4*)hWb);
    agg_kernel<<<agg_grid, 256, 0, stream>>>(hWb, b1, dinv, row_off, indeg, csr, (uint4*)hb);
    gemm_mfma<<<GEMM_BLOCKS, 256, 0, stream>>>((const unsigned short*)hb,
                                               (const unsigned short*)WT2, (uint4*)hWb);
    agg_kernel<<<agg_grid, 256, 0, stream>>>(hWb, b2, dinv, row_off, indeg, csr, (uint4*)hb);
    gemm_mfma<<<GEMM_BLOCKS, 256, 0, stream>>>((const unsigned short*)hb,
                                               (const unsigned short*)WT3, (uint4*)hWb);
    agg_kernel<<<agg_grid, 256, 0, stream>>>(hWb, b3, dinv, row_off, indeg, csr, (uint4*)hb);
    // layer 4 + FC folded
    gemm32_mfma<<<GEMM_BLOCKS, 256, 0, stream>>>((const unsigned short*)hb, WcT, (uint4*)Gb);
    agg32_kernel<<<agg_grid, 256, 0, stream>>>(Gb, dinv, row_off, indeg, csr, p);

    pool_seg_kernel<<<POOL_BLOCKS, 256, 0, stream>>>(p, batch, pool);
    cnt_bs_kernel<<<1, 64, 0, stream>>>(batch, cnt);
    final_kernel<<<(N_GRAPHS * D_OUT + 255) / 256, 256, 0, stream>>>(pool, cnt, bc, out);
}

// Round 7
// 355.095 us; speedup vs baseline: 3.0191x; 1.1211x over previous
//
#include <hip/hip_runtime.h>

// GCN: 4x GCNConv(128->128, sym norm, self-loops) + FC(128->32) + global mean pool.
// R6->R7: dispatch-count reduction (launch overhead ~6-9us/dispatch measured as the
// cross-round accounting residue). 24 -> 15 dispatches: single memset (indeg|cursor
// contiguous), scan_partials+dinv folded into scan_within, x2b deleted (layer-1 gemm
// packs fp32->bf16 in-register), wt+wc+bc merged into prep, pool+cnt+final merged into
// an atomics-free tail (1 block/graph). MFMA gemms + bf16 gather agg carried from R6.

#define N_NODES 50000
#define N_EDGES 600000
#define D 128
#define D_OUT 32
#define N_GRAPHS 64
#define SCAN_B 1024
#define N_SCAN_BLOCKS ((N_NODES + SCAN_B - 1) / SCAN_B)  // 49
#define GEMM_BLOCKS ((N_NODES + 63) / 64)                // 782

typedef short short8 __attribute__((ext_vector_type(8)));
typedef float floatx4 __attribute__((ext_vector_type(4)));

__device__ inline unsigned bf16rne(float a) {
    unsigned u = __float_as_uint(a);
    return (u + 0x7fffu + ((u >> 16) & 1u)) >> 16;
}
__device__ inline unsigned bf16pair(float a, float b) {
    return bf16rne(a) | (bf16rne(b) << 16);
}
__device__ inline void fma8(float* acc, uint4 r, float w) {
    const unsigned hm = 0xffff0000u;
    acc[0] += w * __uint_as_float(r.x << 16);
    acc[1] += w * __uint_as_float(r.x & hm);
    acc[2] += w * __uint_as_float(r.y << 16);
    acc[3] += w * __uint_as_float(r.y & hm);
    acc[4] += w * __uint_as_float(r.z << 16);
    acc[5] += w * __uint_as_float(r.z & hm);
    acc[6] += w * __uint_as_float(r.w << 16);
    acc[7] += w * __uint_as_float(r.w & hm);
}

// ---------------- graph preprocessing ----------------

__global__ void hist_kernel(const int* __restrict__ dst, int* __restrict__ indeg) {
    int e = blockIdx.x * blockDim.x + threadIdx.x;
    if (e < N_EDGES) atomicAdd(&indeg[dst[e]], 1);
}

__global__ void scan_block_sum(const int* __restrict__ indeg, int* __restrict__ bsum) {
    __shared__ int sdata[SCAN_B];
    int i = blockIdx.x * SCAN_B + threadIdx.x;
    sdata[threadIdx.x] = (i < N_NODES) ? indeg[i] : 0;
    __syncthreads();
    for (int s = SCAN_B / 2; s > 0; s >>= 1) {
        if (threadIdx.x < s) sdata[threadIdx.x] += sdata[threadIdx.x + s];
        __syncthreads();
    }
    if (threadIdx.x == 0) bsum[blockIdx.x] = sdata[0];
}

// exclusive scan within block + cross-block offset (49 bsums reduced in-wave) + dinv.
__global__ void scan_within(const int* __restrict__ indeg, const int* __restrict__ bsum,
                            int* __restrict__ row_off, float* __restrict__ dinv) {
    __shared__ int sdata[SCAN_B];
    __shared__ int s_boff;
    int i = blockIdx.x * SCAN_B + threadIdx.x;
    int orig = (i < N_NODES) ? indeg[i] : 0;
    if (threadIdx.x < 64) {  // blockIdx.x <= 48 < 64
        int v = ((int)threadIdx.x < (int)blockIdx.x) ? bsum[threadIdx.x] : 0;
#pragma unroll
        for (int off = 1; off < 64; off <<= 1) v += __shfl_xor(v, off, 64);
        if (threadIdx.x == 0) s_boff = v;
    }
    sdata[threadIdx.x] = orig;
    __syncthreads();
    for (int off = 1; off < SCAN_B; off <<= 1) {
        int add = (threadIdx.x >= (unsigned)off) ? sdata[threadIdx.x - off] : 0;
        __syncthreads();
        if (threadIdx.x >= (unsigned)off) sdata[threadIdx.x] += add;
        __syncthreads();
    }
    if (i < N_NODES) {
        row_off[i] = s_boff + sdata[threadIdx.x] - orig;  // exclusive
        dinv[i] = rsqrtf((float)(orig + 1));              // +1 self-loop
    }
}

__global__ void fill_kernel(const int* __restrict__ src, const int* __restrict__ dst,
                            const int* __restrict__ row_off, int* __restrict__ cursor,
                            const float* __restrict__ dinv,
                            int2* __restrict__ csr) {
    int e = blockIdx.x * blockDim.x + threadIdx.x;
    if (e >= N_EDGES) return;
    int d = dst[e], s = src[e];
    int pos = atomicAdd(&cursor[d], 1);
    int slot = row_off[d] + pos;
    csr[slot] = make_int2(s, __float_as_int(dinv[s] * dinv[d]));
}

// prep: blocks 0-2 transpose W1..W3 -> WT (bf16, WT[n][k]); blocks 3-18 WcT[c][k] =
// bf16((W4@fcW)^T); block 19 bc = b4@fcW + fcb.
__global__ __launch_bounds__(256) void prep_kernel(
        const float* __restrict__ W1, const float* __restrict__ W2,
        const float* __restrict__ W3, const float* __restrict__ W4,
        const float* __restrict__ fcW, const float* __restrict__ fcb,
        const float* __restrict__ b4,
        unsigned* __restrict__ WT1, unsigned* __restrict__ WT2,
        unsigned* __restrict__ WT3, unsigned short* __restrict__ WcT,
        float* __restrict__ bc) {
    __shared__ float smem[128 * 128];
    int b = blockIdx.x, t = threadIdx.x;
    if (b < 3) {
        const float* W = (b == 0) ? W1 : (b == 1) ? W2 : W3;
        unsigned* WT = (b == 0) ? WT1 : (b == 1) ? WT2 : WT3;
        const float4* W4v = (const float4*)W;
        float4* L4 = (float4*)smem;
        for (int i = 0; i < 16; ++i) L4[i * 256 + t] = W4v[i * 256 + t];
        __syncthreads();
        int n = t >> 1, hf = t & 1;
        uint4* WT4 = (uint4*)WT;
        for (int i = 0; i < 8; ++i) {
            int k0 = hf * 64 + i * 8;
            uint4 pk;
            pk.x = bf16pair(smem[(k0 + 0) * 128 + n], smem[(k0 + 1) * 128 + n]);
            pk.y = bf16pair(smem[(k0 + 2) * 128 + n], smem[(k0 + 3) * 128 + n]);
            pk.z = bf16pair(smem[(k0 + 4) * 128 + n], smem[(k0 + 5) * 128 + n]);
            pk.w = bf16pair(smem[(k0 + 6) * 128 + n], smem[(k0 + 7) * 128 + n]);
            WT4[n * 16 + hf * 8 + i] = pk;
        }
    } else if (b < 19) {
        int bb = b - 3;
        for (int i = 0; i < 16; ++i) smem[i * 256 + t] = fcW[i * 256 + t];  // F[128][32]
        __syncthreads();
        int c = t & 31, il = t >> 5;
        int i = bb * 8 + il;  // k index
        float acc = 0.f;
        for (int k = 0; k < 128; ++k) acc += W4[i * 128 + k] * smem[k * 32 + c];
        WcT[c * 128 + i] = (unsigned short)bf16rne(acc);
    } else {
        if (t < 32) {
            float acc = fcb[t];
            for (int k = 0; k < 128; ++k) acc += b4[k] * fcW[k * 32 + t];
            bc[t] = acc;
        }
    }
}

// ---------------- MFMA GEMMs ----------------

// Layer-1: A fp32, packed to bf16 in-register. out = bf16(A @ W), WT[n][k] bf16.
__global__ __launch_bounds__(256) void gemm_mfma_f32(const float* __restrict__ A,
                                                     const unsigned short* __restrict__ WT,
                                                     uint4* __restrict__ outb) {
    __shared__ unsigned short tile[4][16 * 136];
    int t = threadIdx.x;
    int wave = t >> 6, lane = t & 63;
    int row0 = blockIdx.x * 64 + wave * 16;
    int lm = lane & 15, lg = lane >> 4;

    int arow = row0 + lm;
    if (arow >= N_NODES) arow = N_NODES - 1;
    const float4* Arow = (const float4*)(A + (size_t)arow * 128);
    short8 a[4];
#pragma unroll
    for (int kc = 0; kc < 4; ++kc) {
        float4 f0 = Arow[kc * 8 + lg * 2];
        float4 f1 = Arow[kc * 8 + lg * 2 + 1];
        union { short8 s; uint4 u; } cvt;
        cvt.u = make_uint4(bf16pair(f0.x, f0.y), bf16pair(f0.z, f0.w),
                           bf16pair(f1.x, f1.y), bf16pair(f1.z, f1.w));
        a[kc] = cvt.s;
    }

    floatx4 acc[8];
#pragma unroll
    for (int i = 0; i < 8; ++i) acc[i] = (floatx4){0.f, 0.f, 0.f, 0.f};

#pragma unroll
    for (int nt = 0; nt < 8; ++nt) {
        const short8* Brow = (const short8*)(WT + (size_t)(nt * 16 + lm) * 128);
#pragma unroll
        for (int kc = 0; kc < 4; ++kc) {
            short8 bfr = Brow[kc * 4 + lg];
            acc[nt] = __builtin_amdgcn_mfma_f32_16x16x32_bf16(a[kc], bfr, acc[nt], 0, 0, 0);
        }
    }

    unsigned short* T = tile[wave];
#pragma unroll
    for (int nt = 0; nt < 8; ++nt)
#pragma unroll
        for (int r = 0; r < 4; ++r)
            T[(lg * 4 + r) * 136 + nt * 16 + lm] = (unsigned short)bf16rne(acc[nt][r]);
    __syncthreads();
    int rr = lane >> 2, cseg = lane & 3;
    int orow = row0 + rr;
#pragma unroll
    for (int it = 0; it < 4; ++it) {
        uint4 v = *(const uint4*)&T[rr * 136 + cseg * 8 + it * 32];
        if (orow < N_NODES) outb[(size_t)orow * 16 + it * 4 + cseg] = v;
    }
}

// Layers 2-3: A bf16. out = bf16(A @ W).
__global__ __launch_bounds__(256) void gemm_mfma(const unsigned short* __restrict__ Ab,
                                                 const unsigned short* __restrict__ WT,
                                                 uint4* __restrict__ outb) {
    __shared__ unsigned short tile[4][16 * 136];
    int t = threadIdx.x;
    int wave = t >> 6, lane = t & 63;
    int row0 = blockIdx.x * 64 + wave * 16;
    int lm = lane & 15, lg = lane >> 4;

    int arow = row0 + lm;
    if (arow >= N_NODES) arow = N_NODES - 1;
    const short8* Arow = (const short8*)(Ab + (size_t)arow * 128);
    short8 a[4];
#pragma unroll
    for (int kc = 0; kc < 4; ++kc) a[kc] = Arow[kc * 4 + lg];

    floatx4 acc[8];
#pragma unroll
    for (int i = 0; i < 8; ++i) acc[i] = (floatx4){0.f, 0.f, 0.f, 0.f};

#pragma unroll
    for (int nt = 0; nt < 8; ++nt) {
        const short8* Brow = (const short8*)(WT + (size_t)(nt * 16 + lm) * 128);
#pragma unroll
        for (int kc = 0; kc < 4; ++kc) {
            short8 b = Brow[kc * 4 + lg];
            acc[nt] = __builtin_amdgcn_mfma_f32_16x16x32_bf16(a[kc], b, acc[nt], 0, 0, 0);
        }
    }

    unsigned short* T = tile[wave];
#pragma unroll
    for (int nt = 0; nt < 8; ++nt)
#pragma unroll
        for (int r = 0; r < 4; ++r)
            T[(lg * 4 + r) * 136 + nt * 16 + lm] = (unsigned short)bf16rne(acc[nt][r]);
    __syncthreads();
    int rr = lane >> 2, cseg = lane & 3;
    int orow = row0 + rr;
#pragma unroll
    for (int it = 0; it < 4; ++it) {
        uint4 v = *(const uint4*)&T[rr * 136 + cseg * 8 + it * 32];
        if (orow < N_NODES) outb[(size_t)orow * 16 + it * 4 + cseg] = v;
    }
}

// G = bf16(A @ Wc): WcT [32][128] bf16, out [N][32] bf16.
__global__ __launch_bounds__(256) void gemm32_mfma(const unsigned short* __restrict__ Ab,
                                                   const unsigned short* __restrict__ WcT,
                                                   uint4* __restrict__ outb) {
    __shared__ unsigned short tile[4][16 * 32];
    int t = threadIdx.x;
    int wave = t >> 6, lane = t & 63;
    int row0 = blockIdx.x * 64 + wave * 16;
    int lm = lane & 15, lg = lane >> 4;

    int arow = row0 + lm;
    if (arow >= N_NODES) arow = N_NODES - 1;
    const short8* Arow = (const short8*)(Ab + (size_t)arow * 128);
    short8 a[4];
#pragma unroll
    for (int kc = 0; kc < 4; ++kc) a[kc] = Arow[kc * 4 + lg];

    floatx4 acc[2];
#pragma unroll
    for (int i = 0; i < 2; ++i) acc[i] = (floatx4){0.f, 0.f, 0.f, 0.f};

#pragma unroll
    for (int nt = 0; nt < 2; ++nt) {
        const short8* Brow = (const short8*)(WcT + (size_t)(nt * 16 + lm) * 128);
#pragma unroll
        for (int kc = 0; kc < 4; ++kc) {
            short8 b = Brow[kc * 4 + lg];
            acc[nt] = __builtin_amdgcn_mfma_f32_16x16x32_bf16(a[kc], b, acc[nt], 0, 0, 0);
        }
    }

    unsigned short* T = tile[wave];
#pragma unroll
    for (int nt = 0; nt < 2; ++nt)
#pragma unroll
        for (int r = 0; r < 4; ++r)
            T[(lg * 4 + r) * 32 + nt * 16 + lm] = (unsigned short)bf16rne(acc[nt][r]);
    __syncthreads();
    int rr = lane >> 2, cseg = lane & 3;
    int orow = row0 + rr;
    uint4 v = *(const uint4*)&T[rr * 32 + cseg * 8];
    if (orow < N_NODES) outb[(size_t)orow * 4 + cseg] = v;
}

// ---------------- aggregation ----------------

// One wave/node; quarter-wave (16 lanes)/edge, uint4/lane = 8 bf16 dims. Output bf16 row.
__global__ __launch_bounds__(256) void agg_kernel(const unsigned* __restrict__ hWb,
                                                  const float* __restrict__ bias,
                                                  const float* __restrict__ dinv,
                                                  const int* __restrict__ row_off,
                                                  const int* __restrict__ indeg,
                                                  const int2* __restrict__ csr,
                                                  uint4* __restrict__ outb) {
    int wave = threadIdx.x >> 6;
    int lane = threadIdx.x & 63;
    int n = blockIdx.x * 4 + wave;
    if (n >= N_NODES) return;
    int q = lane >> 4;
    int c = lane & 15;
    const uint4* hW4 = (const uint4*)hWb;

    float acc[8] = {0.f, 0.f, 0.f, 0.f, 0.f, 0.f, 0.f, 0.f};
    int beg = row_off[n];
    int end = beg + indeg[n];
    int e = beg + q;
    while (e + 4 < end) {
        int2 e0 = csr[e];
        int2 e1 = csr[e + 4];
        uint4 r0 = hW4[e0.x * 16 + c];
        uint4 r1 = hW4[e1.x * 16 + c];
        fma8(acc, r0, __int_as_float(e0.y));
        fma8(acc, r1, __int_as_float(e1.y));
        e += 8;
    }
    if (e < end) {
        int2 e0 = csr[e];
        uint4 r0 = hW4[e0.x * 16 + c];
        fma8(acc, r0, __int_as_float(e0.y));
    }
#pragma unroll
    for (int i = 0; i < 8; ++i) {
        acc[i] += __shfl_xor(acc[i], 16, 64);
        acc[i] += __shfl_xor(acc[i], 32, 64);
    }
    if (q == 0) {
        float di = dinv[n];
        float sw = di * di;
        uint4 hv = hW4[n * 16 + c];
        fma8(acc, hv, sw);
        float4 bA = ((const float4*)bias)[c * 2];
        float4 bB = ((const float4*)bias)[c * 2 + 1];
        uint4 pk;
        pk.x = bf16pair(acc[0] + bA.x, acc[1] + bA.y);
        pk.y = bf16pair(acc[2] + bA.z, acc[3] + bA.w);
        pk.z = bf16pair(acc[4] + bB.x, acc[5] + bB.y);
        pk.w = bf16pair(acc[6] + bB.z, acc[7] + bB.w);
        outb[(size_t)n * 16 + c] = pk;
    }
}

// 32-dim agg on bf16 G -> p fp32 (no bias; bc folded into tail).
__global__ __launch_bounds__(256) void agg32_kernel(const unsigned* __restrict__ Gb,
                                                    const float* __restrict__ dinv,
                                                    const int* __restrict__ row_off,
                                                    const int* __restrict__ indeg,
                                                    const int2* __restrict__ csr,
                                                    float* __restrict__ p) {
    int wave = threadIdx.x >> 6;
    int lane = threadIdx.x & 63;
    int n = blockIdx.x * 4 + wave;
    if (n >= N_NODES) return;
    int q = lane >> 4;
    int c = lane & 15;

    const unsigned hm = 0xffff0000u;
    float a0 = 0.f, a1 = 0.f;
    int beg = row_off[n];
    int end = beg + indeg[n];
    int e = beg + q;
    while (e + 4 < end) {
        int2 e0 = csr[e];
        int2 e1 = csr[e + 4];
        unsigned r0 = Gb[e0.x * 16 + c];
        unsigned r1 = Gb[e1.x * 16 + c];
        float w0 = __int_as_float(e0.y), w1 = __int_as_float(e1.y);
        a0 += w0 * __uint_as_float(r0 << 16) + w1 * __uint_as_float(r1 << 16);
        a1 += w0 * __uint_as_float(r0 & hm) + w1 * __uint_as_float(r1 & hm);
        e += 8;
    }
    if (e < end) {
        int2 e0 = csr[e];
        unsigned r0 = Gb[e0.x * 16 + c];
        float w0 = __int_as_float(e0.y);
        a0 += w0 * __uint_as_float(r0 << 16);
        a1 += w0 * __uint_as_float(r0 & hm);
    }
    a0 += __shfl_xor(a0, 16, 64); a0 += __shfl_xor(a0, 32, 64);
    a1 += __shfl_xor(a1, 16, 64); a1 += __shfl_xor(a1, 32, 64);
    if (q == 0) {
        float di = dinv[n];
        float sw = di * di;
        unsigned sv = Gb[n * 16 + c];
        a0 += sw * __uint_as_float(sv << 16);
        a1 += sw * __uint_as_float(sv & hm);
        ((float2*)p)[n * 16 + c] = make_float2(a0, a1);
    }
}

// tail: one block per graph (batch SORTED -> contiguous range via binary search).
// out[g] = mean(p rows) + bc. No atomics, no pool buffer.
__global__ __launch_bounds__(256) void tail_kernel(const float* __restrict__ p,
                                                   const int* __restrict__ batch,
                                                   const float* __restrict__ bc,
                                                   float* __restrict__ out) {
    __shared__ float partial[8][32];
    int g = blockIdx.x;
    int t = threadIdx.x;
    int rg = t >> 5, d = t & 31;
    int lo = 0, hi = N_NODES;
    while (lo < hi) { int m = (lo + hi) >> 1; if (batch[m] < g) lo = m + 1; else hi = m; }
    int lo2 = lo, hi2 = N_NODES;
    while (lo2 < hi2) { int m = (lo2 + hi2) >> 1; if (batch[m] < g + 1) lo2 = m + 1; else hi2 = m; }
    int cnt = lo2 - lo;

    float acc = 0.f;
    int n = lo + rg;
    for (; n + 24 < lo2; n += 32) {
        float v0 = p[n * 32 + d];
        float v1 = p[(n + 8) * 32 + d];
        float v2 = p[(n + 16) * 32 + d];
        float v3 = p[(n + 24) * 32 + d];
        acc += (v0 + v1) + (v2 + v3);
    }
    for (; n < lo2; n += 8) acc += p[n * 32 + d];
    partial[rg][d] = acc;
    __syncthreads();
    if (rg == 0) {
        float s = 0.f;
#pragma unroll
        for (int r = 0; r < 8; ++r) s += partial[r][d];
        out[g * 32 + d] = (cnt > 0) ? s / (float)cnt + bc[d] : 0.f;
    }
}

// ---------------- launch ----------------

static inline size_t align_up(size_t x) { return (x + 255) & ~(size_t)255; }

extern "C" void kernel_launch(void* const* d_in, const int* in_sizes, int n_in,
                              void* d_out, int out_size, void* d_ws, size_t ws_size,
                              hipStream_t stream) {
    const float* x = (const float*)d_in[0];
    const int* edge_index = (const int*)d_in[1];
    const int* batch = (const int*)d_in[2];
    const float* W1 = (const float*)d_in[3];
    const float* b1 = (const float*)d_in[4];
    const float* W2 = (const float*)d_in[5];
    const float* b2 = (const float*)d_in[6];
    const float* W3 = (const float*)d_in[7];
    const float* b3 = (const float*)d_in[8];
    const float* W4 = (const float*)d_in[9];
    const float* b4 = (const float*)d_in[10];
    const float* fcW = (const float*)d_in[11];
    const float* fcb = (const float*)d_in[12];
    float* out = (float*)d_out;

    const int* src = edge_index;
    const int* dst = edge_index + N_EDGES;

    char* base = (char*)d_ws;
    size_t o = 0;
    unsigned* hWb = (unsigned*)(base + o);  o = align_up(o + (size_t)N_NODES * D * 2);
    unsigned* hb = (unsigned*)(base + o);   o = align_up(o + (size_t)N_NODES * D * 2);
    int2* csr = (int2*)(base + o);          o = align_up(o + (size_t)N_EDGES * 8);
    int* row_off = (int*)(base + o);        o = align_up(o + (size_t)N_NODES * 4);
    int* deg2 = (int*)(base + o);           o = align_up(o + (size_t)2 * N_NODES * 4);
    int* indeg = deg2;                       // [0,N)
    int* cursor = deg2 + N_NODES;            // [N,2N)  -- one memset covers both
    float* dinv = (float*)(base + o);       o = align_up(o + (size_t)N_NODES * 4);
    int* bsum = (int*)(base + o);           o = align_up(o + 256);
    unsigned* WT1 = (unsigned*)(base + o);  o = align_up(o + (size_t)D * D * 2);
    unsigned* WT2 = (unsigned*)(base + o);  o = align_up(o + (size_t)D * D * 2);
    unsigned* WT3 = (unsigned*)(base + o);  o = align_up(o + (size_t)D * D * 2);
    unsigned short* WcT = (unsigned short*)(base + o); o = align_up(o + (size_t)D * D_OUT * 2);
    float* bc = (float*)(base + o);         o = align_up(o + (size_t)D_OUT * 4);
    float* p = (float*)(base + o);          o = align_up(o + (size_t)N_NODES * D_OUT * 4);
    unsigned* Gb = hWb;  // layer-4 G (bf16) reuses dead hWb slot

    // 1 memset (indeg+cursor contiguous)
    hipMemsetAsync(deg2, 0, (size_t)2 * N_NODES * 4, stream);

    hist_kernel<<<(N_EDGES + 255) / 256, 256, 0, stream>>>(dst, indeg);
    scan_block_sum<<<N_SCAN_BLOCKS, SCAN_B, 0, stream>>>(indeg, bsum);
    scan_within<<<N_SCAN_BLOCKS, SCAN_B, 0, stream>>>(indeg, bsum, row_off, dinv);
    fill_kernel<<<(N_EDGES + 255) / 256, 256, 0, stream>>>(src, dst, row_off, cursor, dinv, csr);
    prep_kernel<<<20, 256, 0, stream>>>(W1, W2, W3, W4, fcW, fcb, b4,
                                        WT1, WT2, WT3, WcT, bc);

    const int agg_grid = (N_NODES + 3) / 4;  // 12500

    gemm_mfma_f32<<<GEMM_BLOCKS, 256, 0, stream>>>(x, (const unsigned short*)WT1, (uint4*)hWb);
    agg_kernel<<<agg_grid, 256, 0, stream>>>(hWb, b1, dinv, row_off, indeg, csr, (uint4*)hb);
    gemm_mfma<<<GEMM_BLOCKS, 256, 0, stream>>>((const unsigned short*)hb,
                                               (const unsigned short*)WT2, (uint4*)hWb);
    agg_kernel<<<agg_grid, 256, 0, stream>>>(hWb, b2, dinv, row_off, indeg, csr, (uint4*)hb);
    gemm_mfma<<<GEMM_BLOCKS, 256, 0, stream>>>((const unsigned short*)hb,
                                               (const unsigned short*)WT3, (uint4*)hWb);
    agg_kernel<<<agg_grid, 256, 0, stream>>>(hWb, b3, dinv, row_off, indeg, csr, (uint4*)hb);
    // layer 4 + FC folded
    gemm32_mfma<<<GEMM_BLOCKS, 256, 0, stream>>>((const unsigned short*)hb, WcT, (uint4*)Gb);
    agg32_kernel<<<agg_grid, 256, 0, stream>>>(Gb, dinv, row_off, indeg, csr, p);

    tail_kernel<<<N_GRAPHS, 256, 0, stream>>>(p, batch, bc, out);
}